// Round 12
// baseline (5851.306 us; speedup 1.0000x reference)
//
#include <hip/hip_runtime.h>
#include <stdint.h>

typedef _Float16 f16;
typedef f16  f16x8 __attribute__((ext_vector_type(8)));
typedef float f32x4 __attribute__((ext_vector_type(4)));
typedef unsigned u32x4 __attribute__((ext_vector_type(4)));

// ---------------- ws layout (byte offsets) ----------------
// H0/H1: 2 bufs x [k/8][b][hi8|lo8] f16 (1 MB per buf); cached reads + inv barriers
// WIH1F: fp16 MFMA A-frags of Wih1, [hgrp128][frag64][lane64][8] = 8 MB (read-only)
// SEQ [84][256] f32 | YACC [24][256] f32 | FLAG 256x128B + 16x128B group flags
#define H0_OFF    0u
#define H1_OFF    2097152u
#define WIH1F_OFF 4194304u
#define SEQ_OFF   12582912u
#define YACC_OFF  12668928u
#define FLAG_OFF  12693504u

__device__ __forceinline__ unsigned rotl32(unsigned x, int d){ return (x<<d)|(x>>(32-d)); }

// Threefry-2x32, 20 rounds, exactly JAX's key schedule. (bit-exact, proven R1-R11)
__device__ __forceinline__ uint2 tf2x32(unsigned k0, unsigned k1, unsigned x0, unsigned x1){
  unsigned kx = k0 ^ k1 ^ 0x1BD11BDAu;
  x0 += k0; x1 += k1;
#define TFR(r) { x0 += x1; x1 = rotl32(x1,(r)); x1 ^= x0; }
  TFR(13) TFR(15) TFR(26) TFR(6)  x0 += k1; x1 += kx + 1u;
  TFR(17) TFR(29) TFR(16) TFR(24) x0 += kx; x1 += k0 + 2u;
  TFR(13) TFR(15) TFR(26) TFR(6)  x0 += k0; x1 += k1 + 3u;
  TFR(17) TFR(29) TFR(16) TFR(24) x0 += k1; x1 += kx + 4u;
  TFR(13) TFR(15) TFR(26) TFR(6)  x0 += kx; x1 += k0 + 5u;
#undef TFR
  return make_uint2(x0, x1);
}

__device__ __forceinline__ bool drop_keep(uint2 fk, unsigned n){
  uint2 o = tf2x32(fk.x, fk.y, 0u, n);
  unsigned bits = o.x ^ o.y;
  float u = __uint_as_float((bits >> 9) | 0x3f800000u) - 1.0f;
  return u < 0.8f;
}

__device__ __forceinline__ float sigf(float x){ return 1.0f/(1.0f + __expf(-x)); }
__device__ __forceinline__ float thf(float x){ return 1.0f - 2.0f/(__expf(2.0f*x) + 1.0f); }

// ---- LLC-coherent accessors for flags/scalars/publication (proven R4-R11) ----
__device__ __forceinline__ void st_dword_sc(void* p, unsigned v){
  asm volatile("global_store_dword %0, %1, off sc0 sc1" :: "v"(p), "v"(v) : "memory");
}
__device__ __forceinline__ void st_dwordx4_sc(void* p, u32x4 v){
  asm volatile("global_store_dwordx4 %0, %1, off sc0 sc1" :: "v"(p), "v"(v) : "memory");
}
__device__ __forceinline__ unsigned ld_dword_sc(const void* p){
  unsigned r;
  asm volatile("global_load_dword %0, %1, off sc0 sc1\n\ts_waitcnt vmcnt(0)"
               : "=v"(r) : "v"(p) : "memory");
  return r;
}
// async CACHED 16B load (no internal wait); waits inserted manually via VMW(N).
__device__ __forceinline__ void ldx4_c(f16x8& d, const f16* p){
  asm volatile("global_load_dwordx4 %0, %1, off" : "=&v"(d) : "v"(p));
}
#define VMW(N) do{ asm volatile("s_waitcnt vmcnt(" #N ")"); __builtin_amdgcn_sched_barrier(0); }while(0)

// 2-level tree grid barrier (proven R10/R11); inv optional per call site.
__device__ __forceinline__ void gbar(unsigned* flags, unsigned* gflags, unsigned e,
                                     int tid, int blk, bool inv){
  asm volatile("s_waitcnt vmcnt(0)" ::: "memory");
  __syncthreads();
  if (tid == 0) st_dword_sc(flags + blk*32, e);
  if (blk < 16){
    if (tid < 16){
      unsigned* f = flags + (blk*16 + tid)*32;
      while (ld_dword_sc(f) < e) __builtin_amdgcn_s_sleep(1);
    }
    __syncthreads();
    if (tid == 0) st_dword_sc(gflags + blk*32, e);
  }
  if (tid < 16){
    unsigned* f = gflags + tid*32;
    while (ld_dword_sc(f) < e) __builtin_amdgcn_s_sleep(1);
  }
  __syncthreads();
  if (inv) __builtin_amdgcn_fence(__ATOMIC_ACQUIRE, "agent");
  __builtin_amdgcn_sched_barrier(0);
}

// ---- prep: zero h buffers + y_acc + flags (incl. group flags) ----
__global__ void k_init(uint4* __restrict__ hz, uint4* __restrict__ yz, uint4* __restrict__ fz){
  unsigned i = blockIdx.x*256u + threadIdx.x;
  if (i < 262144u){ hz[i] = uint4{0,0,0,0}; }
  else if (i < 263680u){ yz[i - 262144u] = uint4{0,0,0,0}; }
  else if (i < 265856u){ fz[i - 263680u] = uint4{0,0,0,0}; }
}

// ---- prep: conv1d(pad1,k3) + relu + maxpool2 -> seq[84][256] ----
__global__ void k_seq(const float* __restrict__ x, const float* __restrict__ cw,
                      const float* __restrict__ cb, float* __restrict__ seq){
  const int q = blockIdx.x;
  const int b = threadIdx.x;
  float best = -1e30f;
#pragma unroll
  for (int ssub = 0; ssub < 2; ++ssub){
    int p = 2*q + ssub;
    float acc = cb[0];
#pragma unroll
    for (int k = 0; k < 3; ++k){
      int t = p - 1 + k;
      if (t >= 0 && t < 168){
        const float* xp = x + ((size_t)b*192 + t)*8;
#pragma unroll
        for (int i = 0; i < 8; ++i) acc = fmaf(xp[i], cw[i*3 + k], acc);
      }
    }
    acc  = fmaxf(acc, 0.0f);
    best = fmaxf(best, acc);
  }
  seq[(q<<8) + b] = best;
}

// ---- prep: pack Wih1 (fp32 [4096][1024]) into fp16 MFMA A-frags per hgrp ----
__global__ void __launch_bounds__(512) k_wpack(const float* __restrict__ W, f16* __restrict__ dst){
  const int hgrp = blockIdx.x;       // 0..127
  const int tid = threadIdx.x;
  const int l   = tid & 63;
  const int w   = tid >> 6;          // 0..7
  const int j0  = hgrp << 3;
#pragma unroll
  for (int fi = 0; fi < 8; ++fi){
    const int f = (w << 3) + fi;     // 0..63
    const int c = f >> 1, T = f & 1;
    const int r = l & 15;
    const int u = (T << 2) + (r >> 2);
    const int g = r & 3;
    const float* src = W + (((size_t)((g << 10) + j0 + u)) << 10) + (c << 5) + ((l >> 4) << 3);
    float4 a = *(const float4*)src;
    float4 b = *(const float4*)(src + 4);
    f16x8 v;
    v[0]=(f16)a.x; v[1]=(f16)a.y; v[2]=(f16)a.z; v[3]=(f16)a.w;
    v[4]=(f16)b.x; v[5]=(f16)b.y; v[6]=(f16)b.z; v[7]=(f16)b.w;
    *(f16x8*)(dst + ((size_t)hgrp << 15) + (f << 9) + (l << 3)) = v;
  }
}

#define MFMA16(a,b,c) __builtin_amdgcn_mfma_f32_16x16x32_f16((a),(b),(c),0,0,0)

// ---- main: 256 blocks (128 hgrp x 2 bgrp) x 512 threads (8 col-group waves) ----
// NOTE: min-waves = 1 (NOT 2): LDS 132KB forces 1 block/CU anyway; (512,2) was
// silently capping VGPR at 128 and strangling the load pipeline (R7-R11 bug).
__global__ void __launch_bounds__(512, 1) k_main(
    const float* __restrict__ Wih0, const float* __restrict__ Whh0,
    const float* __restrict__ bih0, const float* __restrict__ bhh0,
    const float* __restrict__ Wih1, const float* __restrict__ Whh1,
    const float* __restrict__ bih1, const float* __restrict__ bhh1,
    const float* __restrict__ fc_w, const float* __restrict__ fc_b,
    char* __restrict__ ws, float* __restrict__ out)
{
  extern __shared__ char smem_[];
  f16* lds = (f16*)smem_;          // halves: [0,32768) Whh0 frags | [32768,65536) Whh1 frags
  f16* stage = lds + 65536;        // 2048 halves: [128 local cols][hi8|lo8]

  const int tid  = threadIdx.x;
  const int blk  = blockIdx.x;
  const int hgrp = blk & 127;      // hidden units 8*hgrp..+7
  const int bgrp = blk >> 7;       // batch cols bgrp*128..+127
  const int j0   = hgrp << 3;
  const int l    = tid & 63;
  const int w8   = tid >> 6;       // wave 0..7, local cols w8*16..+16
  const int q    = l >> 4;
  const int c16  = l & 15;
  const int lcol = (w8 << 4) + c16;     // 0..127
  const int bcol = (bgrp << 7) + lcol;  // absolute batch col

  // ---- pack Whh0, Whh1 slices into LDS as MFMA A-frags (once) ----
  {
    const float* srcs[2] = {Whh0, Whh1};
#pragma unroll
    for (int m = 0; m < 2; ++m){
#pragma unroll
      for (int fi = 0; fi < 8; ++fi){
        const int f = (w8 << 3) + fi;
        const int c = f >> 1, T = f & 1;
        const int r = c16;
        const int uu = (T << 2) + (r >> 2);
        const int g = r & 3;
        const float* src = srcs[m] + (((size_t)((g << 10) + j0 + uu)) << 10) + (c << 5) + (q << 3);
        float4 a = *(const float4*)src;
        float4 b = *(const float4*)(src + 4);
        f16x8 v;
        v[0]=(f16)a.x; v[1]=(f16)a.y; v[2]=(f16)a.z; v[3]=(f16)a.w;
        v[4]=(f16)b.x; v[5]=(f16)b.y; v[6]=(f16)b.z; v[7]=(f16)b.w;
        *(f16x8*)(lds + m*32768 + (f << 9) + (l << 3)) = v;
      }
    }
  }
  __syncthreads();

  // ---- per-lane constants (units q and q+4) ----
  float bias0t[2][4], bias1t[2][4], wi0t[2][4];
#pragma unroll
  for (int t = 0; t < 2; ++t){
    const int uu = j0 + q + t*4;
#pragma unroll
    for (int g = 0; g < 4; ++g){
      int row = (g << 10) + uu;
      bias0t[t][g] = bih0[row] + bhh0[row];
      bias1t[t][g] = bih1[row] + bhh1[row];
      wi0t[t][g]   = Wih0[row];
    }
  }
  const float fcw0 = fc_w[j0 + q] * 1.25f;
  const float fcw1 = fc_w[j0 + q + 4] * 1.25f;
  const float fcb  = fc_b[0];

  const int base_h = (q << 12) + (bcol << 4);   // per-lane B-frag offset (halves)

  f16* H0 = (f16*)(ws + H0_OFF);   // per-buf 524288 halves
  f16* H1 = (f16*)(ws + H1_OFF);
  const f16* wih1f = (const f16*)(ws + WIH1F_OFF) + ((size_t)hgrp << 15);
  const float* seq = (const float*)(ws + SEQ_OFF);
  float* y_acc = (float*)(ws + YACC_OFF);
  unsigned* flags  = (unsigned*)(ws + FLAG_OFF);
  unsigned* gflags = flags + 256*32;

  float c0[2] = {0,0}, c1[2] = {0,0};
  float yprev = 0.f;
  unsigned ep = 0;

#pragma unroll 1
  for (int s = 0; s < 107; ++s){
    const int src = s & 1, dst = src ^ 1;

    if (s >= 84){
      const int tp = s - 84;
      yprev = fcb + __uint_as_float(ld_dword_sc(y_acc + (tp << 8) + bcol));
      if (hgrp == 0 && q == 0) out[bcol*24 + tp] = yprev;
    }
    // resolve x_t BEFORE the counted-vmcnt region
    float xb = (s < 84) ? seq[(s << 8) + bcol] : yprev;
    asm volatile("" :: "v"(xb));

    // ========= phase A: gates0 = Whh0*(h0hi+h0lo)  [LDS weights + cached h, 24-deep] =========
    float h0n[2];
    {
      const f16* a0 = H0 + src*524288 + base_h;
      f16x8 Bh[4][4], Bl[4][4];
      f32x4 accA0 = (f32x4){0,0,0,0}, accA1 = (f32x4){0,0,0,0};
      asm volatile("s_waitcnt vmcnt(0)" ::: "memory");   // region entry: count = 0
      __builtin_amdgcn_sched_barrier(0);
#define ISSA(B, CB) { _Pragma("unroll") for (int i = 0; i < 4; ++i){ const int c = (CB)+i; \
      ldx4_c(Bh[B][i], a0 + c*16384); ldx4_c(Bl[B][i], a0 + c*16384 + 8); } }
#define MMPA(B, CB) { _Pragma("unroll") for (int i = 0; i < 4; ++i){ const int c = (CB)+i; \
      f16x8 wf0 = *(const f16x8*)(lds + ((2*c  ) << 9) + (l << 3)); \
      f16x8 wf1 = *(const f16x8*)(lds + ((2*c+1) << 9) + (l << 3)); \
      accA0 = MFMA16(wf0, Bh[B][i], accA0); accA0 = MFMA16(wf0, Bl[B][i], accA0); \
      accA1 = MFMA16(wf1, Bh[B][i], accA1); accA1 = MFMA16(wf1, Bl[B][i], accA1); } }
      ISSA(0, 0) ISSA(1, 4) ISSA(2, 8)          // 24 loads in flight
#pragma unroll
      for (int cb = 0; cb < 8; ++cb){
        if (cb <= 5) VMW(16); else if (cb == 6) VMW(8); else VMW(0);
        if      ((cb & 3) == 0){ MMPA(0, cb*4) if (cb < 5) ISSA(3, (cb+3)*4) }
        else if ((cb & 3) == 1){ MMPA(1, cb*4) if (cb < 5) ISSA(0, (cb+3)*4) }
        else if ((cb & 3) == 2){ MMPA(2, cb*4) if (cb < 5) ISSA(1, (cb+3)*4) }
        else                   { MMPA(3, cb*4) if (cb < 5) ISSA(2, (cb+3)*4) }
      }
#undef ISSA
#undef MMPA
      __builtin_amdgcn_sched_barrier(0);
      f32x4 at[2] = {accA0, accA1};
#pragma unroll
      for (int t = 0; t < 2; ++t){
        float pi = at[t][0] + bias0t[t][0] + wi0t[t][0]*xb;
        float pf = at[t][1] + bias0t[t][1] + wi0t[t][1]*xb;
        float pg = at[t][2] + bias0t[t][2] + wi0t[t][2]*xb;
        float po = at[t][3] + bias0t[t][3] + wi0t[t][3]*xb;
        c0[t]  = sigf(pf)*c0[t] + sigf(pi)*thf(pg);
        h0n[t] = sigf(po)*thf(c0[t]);
        f16 hi = (f16)h0n[t];
        f16 lo = (f16)(h0n[t] - (float)hi);
        stage[(lcol << 4) + q + t*4]     = hi;
        stage[(lcol << 4) + 8 + q + t*4] = lo;
      }
    }
    __syncthreads();
    if (tid < 256){
      u32x4 v = ((const u32x4*)stage)[tid];
      st_dwordx4_sc((char*)(H0 + dst*524288 + (hgrp << 12) + (bgrp << 11)) + tid*16, v);
    }
    ++ep; gbar(flags, gflags, ep, tid, blk, true);   // mid barrier WITH inv

    // ========= phase B: gates1 = Wih1*(h0new) + Whh1*(h1)  [cached, 24-deep] =========
    float h1n[2];
    {
      const f16* b0 = H0 + dst*524288 + base_h;
      const f16* b1 = H1 + src*524288 + base_h;
      const f16* wfp1 = wih1f + (l << 3);
      f16x8 Wa0[2][2], Wa1[2][2], X0h[2][2], X0l[2][2], X1h[2][2], X1l[2][2];
      f32x4 accB0 = (f32x4){0,0,0,0}, accB1 = (f32x4){0,0,0,0};
      asm volatile("s_waitcnt vmcnt(0)" ::: "memory");   // region entry: count = 0
      __builtin_amdgcn_sched_barrier(0);
#define ISSB(B, C0) { _Pragma("unroll") for (int i = 0; i < 2; ++i){ const int c = (C0)+i; \
      ldx4_c(Wa0[B][i], wfp1 + ((2*c  ) << 9)); \
      ldx4_c(Wa1[B][i], wfp1 + ((2*c+1) << 9)); \
      ldx4_c(X0h[B][i], b0 + c*16384); ldx4_c(X0l[B][i], b0 + c*16384 + 8); \
      ldx4_c(X1h[B][i], b1 + c*16384); ldx4_c(X1l[B][i], b1 + c*16384 + 8); } }
#define MMBQ(B, C0) { _Pragma("unroll") for (int i = 0; i < 2; ++i){ const int c = (C0)+i; \
      f16x8 wb0 = *(const f16x8*)(lds + 32768 + ((2*c  ) << 9) + (l << 3)); \
      f16x8 wb1 = *(const f16x8*)(lds + 32768 + ((2*c+1) << 9) + (l << 3)); \
      accB0 = MFMA16(Wa0[B][i], X0h[B][i], accB0); accB0 = MFMA16(Wa0[B][i], X0l[B][i], accB0); \
      accB0 = MFMA16(wb0,       X1h[B][i], accB0); accB0 = MFMA16(wb0,       X1l[B][i], accB0); \
      accB1 = MFMA16(Wa1[B][i], X0h[B][i], accB1); accB1 = MFMA16(Wa1[B][i], X0l[B][i], accB1); \
      accB1 = MFMA16(wb1,       X1h[B][i], accB1); accB1 = MFMA16(wb1,       X1l[B][i], accB1); } }
      ISSB(0, 0) ISSB(1, 2)                     // 24 loads in flight
#pragma unroll
      for (int cb = 0; cb < 16; ++cb){
        if (cb < 15) VMW(12); else VMW(0);
        if ((cb & 1) == 0){ MMBQ(0, cb*2) if (cb < 14) ISSB(0, (cb+2)*2) }
        else              { MMBQ(1, cb*2) if (cb < 14) ISSB(1, (cb+2)*2) }
      }
#undef ISSB
#undef MMBQ
      __builtin_amdgcn_sched_barrier(0);
      f32x4 at[2] = {accB0, accB1};
#pragma unroll
      for (int t = 0; t < 2; ++t){
        float pi = at[t][0] + bias1t[t][0];
        float pf = at[t][1] + bias1t[t][1];
        float pg = at[t][2] + bias1t[t][2];
        float po = at[t][3] + bias1t[t][3];
        c1[t]  = sigf(pf)*c1[t] + sigf(pi)*thf(pg);
        h1n[t] = sigf(po)*thf(c1[t]);
        f16 hi = (f16)h1n[t];
        f16 lo = (f16)(h1n[t] - (float)hi);
        stage[(lcol << 4) + q + t*4]     = hi;
        stage[(lcol << 4) + 8 + q + t*4] = lo;
      }
    }
    __syncthreads();
    if (tid < 256){
      u32x4 v = ((const u32x4*)stage)[tid];
      st_dwordx4_sc((char*)(H1 + dst*524288 + (hgrp << 12) + (bgrp << 11)) + tid*16, v);
    }

    // ---- fc partials with exact JAX dropout (tau = s-83) ----
    if (s >= 83){
      const int tau = s - 83;
      uint2 fk = tf2x32(0u, 42u, 0u, (unsigned)tau);
      unsigned n0 = ((unsigned)bcol << 10) + (unsigned)(j0 + q);
      unsigned n1 = n0 + 4u;
      float v = (drop_keep(fk, n0) ? h1n[0]*fcw0 : 0.f)
              + (drop_keep(fk, n1) ? h1n[1]*fcw1 : 0.f);
      v += __shfl_xor(v, 16, 64);
      v += __shfl_xor(v, 32, 64);
      if (q == 0) atomicAdd(y_acc + (tau << 8) + bcol, v);
      ++ep; gbar(flags, gflags, ep, tid, blk, false);  // end barrier, NO inv (audited:
      // y_acc crosses via sc-load; h0/h1 reads re-guarded by next mid-barrier inv)
    }
  }

  // tail: y_23 (read via LLC-coherent load)
  if (hgrp == 0 && q == 0)
    out[bcol*24 + 23] = fcb + __uint_as_float(ld_dword_sc(y_acc + (23 << 8) + bcol));
}

extern "C" void kernel_launch(void* const* d_in, const int* in_sizes, int n_in,
                              void* d_out, int out_size, void* d_ws, size_t ws_size,
                              hipStream_t stream)
{
  const float* x    = (const float*)d_in[0];
  const float* cw   = (const float*)d_in[1];
  const float* cb   = (const float*)d_in[2];
  const float* Wih0 = (const float*)d_in[3];
  const float* Whh0 = (const float*)d_in[4];
  const float* bih0 = (const float*)d_in[5];
  const float* bhh0 = (const float*)d_in[6];
  const float* Wih1 = (const float*)d_in[7];
  const float* Whh1 = (const float*)d_in[8];
  const float* bih1 = (const float*)d_in[9];
  const float* bhh1 = (const float*)d_in[10];
  const float* fc_w = (const float*)d_in[11];
  const float* fc_b = (const float*)d_in[12];
  float* out = (float*)d_out;
  char*  ws  = (char*)d_ws;

  hipLaunchKernelGGL(k_init, dim3(1040), dim3(256), 0, stream,
                     (uint4*)(ws + H0_OFF), (uint4*)(ws + YACC_OFF), (uint4*)(ws + FLAG_OFF));
  hipLaunchKernelGGL(k_seq,  dim3(84), dim3(256), 0, stream, x, cw, cb, (float*)(ws + SEQ_OFF));
  hipLaunchKernelGGL(k_wpack, dim3(128), dim3(512), 0, stream, Wih1, (f16*)(ws + WIH1F_OFF));
  hipLaunchKernelGGL(k_main, dim3(256), dim3(512), 135168, stream,
                     Wih0, Whh0, bih0, bhh0, Wih1, Whh1, bih1, bhh1,
                     fc_w, fc_b, ws, out);
}

// Round 13
// 4400.872 us; speedup vs baseline: 1.3296x; 1.3296x over previous
//
#include <hip/hip_runtime.h>
#include <stdint.h>

typedef _Float16 f16;
typedef f16  f16x8 __attribute__((ext_vector_type(8)));
typedef float f32x4 __attribute__((ext_vector_type(4)));
typedef unsigned u32x4 __attribute__((ext_vector_type(4)));

// ---------------- ws layout (byte offsets) ----------------
// H0/H1: 2 bufs x [k/8][b][hi8|lo8] f16 (1 MB per buf)
// WHH0F: fp16 MFMA A-frags of Whh0, [hgrp128][frag64][lane64][8] = 8 MB
// SEQ [84][256] f32 | YACC [24][256] f32 | FLAG 256x128B + 16x128B group flags
#define H0_OFF    0u
#define H1_OFF    2097152u
#define WHH0F_OFF 4194304u
#define SEQ_OFF   12582912u
#define YACC_OFF  12668928u
#define FLAG_OFF  12693504u

__device__ __forceinline__ unsigned rotl32(unsigned x, int d){ return (x<<d)|(x>>(32-d)); }

// Threefry-2x32, 20 rounds, exactly JAX's key schedule. (bit-exact, proven R1-R12)
__device__ __forceinline__ uint2 tf2x32(unsigned k0, unsigned k1, unsigned x0, unsigned x1){
  unsigned kx = k0 ^ k1 ^ 0x1BD11BDAu;
  x0 += k0; x1 += k1;
#define TFR(r) { x0 += x1; x1 = rotl32(x1,(r)); x1 ^= x0; }
  TFR(13) TFR(15) TFR(26) TFR(6)  x0 += k1; x1 += kx + 1u;
  TFR(17) TFR(29) TFR(16) TFR(24) x0 += kx; x1 += k0 + 2u;
  TFR(13) TFR(15) TFR(26) TFR(6)  x0 += k0; x1 += k1 + 3u;
  TFR(17) TFR(29) TFR(16) TFR(24) x0 += k1; x1 += kx + 4u;
  TFR(13) TFR(15) TFR(26) TFR(6)  x0 += kx; x1 += k0 + 5u;
#undef TFR
  return make_uint2(x0, x1);
}

__device__ __forceinline__ bool drop_keep(uint2 fk, unsigned n){
  uint2 o = tf2x32(fk.x, fk.y, 0u, n);
  unsigned bits = o.x ^ o.y;
  float u = __uint_as_float((bits >> 9) | 0x3f800000u) - 1.0f;
  return u < 0.8f;
}

__device__ __forceinline__ float sigf(float x){ return 1.0f/(1.0f + __expf(-x)); }
__device__ __forceinline__ float thf(float x){ return 1.0f - 2.0f/(__expf(2.0f*x) + 1.0f); }

// ---- LLC-coherent accessors for flags/scalars/publication (proven R4-R12) ----
__device__ __forceinline__ void st_dword_sc(void* p, unsigned v){
  asm volatile("global_store_dword %0, %1, off sc0 sc1" :: "v"(p), "v"(v) : "memory");
}
__device__ __forceinline__ void st_dwordx4_sc(void* p, u32x4 v){
  asm volatile("global_store_dwordx4 %0, %1, off sc0 sc1" :: "v"(p), "v"(v) : "memory");
}
__device__ __forceinline__ unsigned ld_dword_sc(const void* p){
  unsigned r;
  asm volatile("global_load_dword %0, %1, off sc0 sc1\n\ts_waitcnt vmcnt(0)"
               : "=v"(r) : "v"(p) : "memory");
  return r;
}

// 2-level tree grid barrier (R10/R12 mechanics); inv optional per call site.
__device__ __forceinline__ void gbar(unsigned* flags, unsigned* gflags, unsigned e,
                                     int tid, int blk, bool inv){
  asm volatile("s_waitcnt vmcnt(0)" ::: "memory");
  __syncthreads();
  if (tid == 0) st_dword_sc(flags + blk*32, e);
  if (blk < 16){
    if (tid < 16){
      unsigned* f = flags + (blk*16 + tid)*32;
      while (ld_dword_sc(f) < e) __builtin_amdgcn_s_sleep(1);
    }
    __syncthreads();
    if (tid == 0) st_dword_sc(gflags + blk*32, e);
  }
  if (tid < 16){
    unsigned* f = gflags + tid*32;
    while (ld_dword_sc(f) < e) __builtin_amdgcn_s_sleep(1);
  }
  __syncthreads();
  if (inv) __builtin_amdgcn_fence(__ATOMIC_ACQUIRE, "agent");
  __builtin_amdgcn_sched_barrier(0);
}

// ---- prep: zero h buffers + y_acc + flags (incl. group flags) ----
__global__ void k_init(uint4* __restrict__ hz, uint4* __restrict__ yz, uint4* __restrict__ fz){
  unsigned i = blockIdx.x*256u + threadIdx.x;
  if (i < 262144u){ hz[i] = uint4{0,0,0,0}; }
  else if (i < 263680u){ yz[i - 262144u] = uint4{0,0,0,0}; }
  else if (i < 265856u){ fz[i - 263680u] = uint4{0,0,0,0}; }
}

// ---- prep: conv1d(pad1,k3) + relu + maxpool2 -> seq[84][256] ----
__global__ void k_seq(const float* __restrict__ x, const float* __restrict__ cw,
                      const float* __restrict__ cb, float* __restrict__ seq){
  const int q = blockIdx.x;
  const int b = threadIdx.x;
  float best = -1e30f;
#pragma unroll
  for (int ssub = 0; ssub < 2; ++ssub){
    int p = 2*q + ssub;
    float acc = cb[0];
#pragma unroll
    for (int k = 0; k < 3; ++k){
      int t = p - 1 + k;
      if (t >= 0 && t < 168){
        const float* xp = x + ((size_t)b*192 + t)*8;
#pragma unroll
        for (int i = 0; i < 8; ++i) acc = fmaf(xp[i], cw[i*3 + k], acc);
      }
    }
    acc  = fmaxf(acc, 0.0f);
    best = fmaxf(best, acc);
  }
  seq[(q<<8) + b] = best;
}

// ---- prep: pack Whh0 (fp32 [4096][1024]) into fp16 MFMA A-frags per hgrp ----
__global__ void __launch_bounds__(512) k_wpack(const float* __restrict__ W, f16* __restrict__ dst){
  const int hgrp = blockIdx.x;       // 0..127
  const int tid = threadIdx.x;
  const int l   = tid & 63;
  const int w   = tid >> 6;          // 0..7
  const int j0  = hgrp << 3;
#pragma unroll
  for (int fi = 0; fi < 8; ++fi){
    const int f = (w << 3) + fi;     // 0..63
    const int c = f >> 1, T = f & 1;
    const int r = l & 15;
    const int u = (T << 2) + (r >> 2);
    const int g = r & 3;
    const float* src = W + (((size_t)((g << 10) + j0 + u)) << 10) + (c << 5) + ((l >> 4) << 3);
    float4 a = *(const float4*)src;
    float4 b = *(const float4*)(src + 4);
    f16x8 v;
    v[0]=(f16)a.x; v[1]=(f16)a.y; v[2]=(f16)a.z; v[3]=(f16)a.w;
    v[4]=(f16)b.x; v[5]=(f16)b.y; v[6]=(f16)b.z; v[7]=(f16)b.w;
    *(f16x8*)(dst + ((size_t)hgrp << 15) + (f << 9) + (l << 3)) = v;
  }
}

#define MFMA16(a,b,c) __builtin_amdgcn_mfma_f32_16x16x32_f16((a),(b),(c),0,0,0)

// ---- main: 256 blocks (128 hgrp x 2 bgrp) x 512 threads (8 col-group waves) ----
__global__ void __launch_bounds__(512, 1) k_main(
    const float* __restrict__ Wih0, const float* __restrict__ Whh0,
    const float* __restrict__ bih0, const float* __restrict__ bhh0,
    const float* __restrict__ Wih1, const float* __restrict__ Whh1,
    const float* __restrict__ bih1, const float* __restrict__ bhh1,
    const float* __restrict__ fc_w, const float* __restrict__ fc_b,
    char* __restrict__ ws, float* __restrict__ out)
{
  extern __shared__ char smem_[];
  f16* lds = (f16*)smem_;          // halves: [0,32768) Wih1 frags | [32768,65536) Whh1 frags
  f16* stage = lds + 65536;        // 2048 halves: [128 local cols][hi8|lo8]

  const int tid  = threadIdx.x;
  const int blk  = blockIdx.x;
  const int hgrp = blk & 127;      // hidden units 8*hgrp..+7
  const int bgrp = blk >> 7;       // batch cols bgrp*128..+127
  const int j0   = hgrp << 3;
  const int l    = tid & 63;
  const int w8   = tid >> 6;       // wave 0..7, local cols w8*16..+16
  const int q    = l >> 4;
  const int c16  = l & 15;
  const int lcol = (w8 << 4) + c16;     // 0..127
  const int bcol = (bgrp << 7) + lcol;  // absolute batch col

  // ---- pack Wih1, Whh1 slices into LDS as MFMA A-frags (once) ----
  {
    const float* srcs[2] = {Wih1, Whh1};
#pragma unroll
    for (int m = 0; m < 2; ++m){
#pragma unroll
      for (int fi = 0; fi < 8; ++fi){
        const int f = (w8 << 3) + fi;
        const int c = f >> 1, T = f & 1;
        const int r = c16;
        const int uu = (T << 2) + (r >> 2);
        const int g = r & 3;
        const float* src = srcs[m] + (((size_t)((g << 10) + j0 + uu)) << 10) + (c << 5) + (q << 3);
        float4 a = *(const float4*)src;
        float4 b = *(const float4*)(src + 4);
        f16x8 v;
        v[0]=(f16)a.x; v[1]=(f16)a.y; v[2]=(f16)a.z; v[3]=(f16)a.w;
        v[4]=(f16)b.x; v[5]=(f16)b.y; v[6]=(f16)b.z; v[7]=(f16)b.w;
        *(f16x8*)(lds + m*32768 + (f << 9) + (l << 3)) = v;
      }
    }
  }
  __syncthreads();

  // ---- per-lane constants (units q and q+4) ----
  float bias0t[2][4], bias1t[2][4], wi0t[2][4];
#pragma unroll
  for (int t = 0; t < 2; ++t){
    const int uu = j0 + q + t*4;
#pragma unroll
    for (int g = 0; g < 4; ++g){
      int row = (g << 10) + uu;
      bias0t[t][g] = bih0[row] + bhh0[row];
      bias1t[t][g] = bih1[row] + bhh1[row];
      wi0t[t][g]   = Wih0[row];
    }
  }
  const float fcw0 = fc_w[j0 + q] * 1.25f;
  const float fcw1 = fc_w[j0 + q + 4] * 1.25f;
  const float fcb  = fc_b[0];

  const int base_h = (q << 12) + (bcol << 4);   // per-lane B-frag offset (halves)

  f16* H0 = (f16*)(ws + H0_OFF);   // per-buf 524288 halves
  f16* H1 = (f16*)(ws + H1_OFF);
  const f16* whh0f = (const f16*)(ws + WHH0F_OFF) + ((size_t)hgrp << 15);
  const float* seq = (const float*)(ws + SEQ_OFF);
  float* y_acc = (float*)(ws + YACC_OFF);
  unsigned* flags  = (unsigned*)(ws + FLAG_OFF);
  unsigned* gflags = flags + 256*32;

  float c0[2] = {0,0}, c1[2] = {0,0};
  float yprev = 0.f;
  unsigned ep = 0;

#pragma unroll 1
  for (int s = 0; s < 107; ++s){
    const int src = s & 1, dst = src ^ 1;

    if (s >= 84){
      const int tp = s - 84;
      // y_acc crosses the (inv-free) end barrier -> LLC-coherent read
      yprev = fcb + __uint_as_float(ld_dword_sc(y_acc + (tp << 8) + bcol));
      if (hgrp == 0 && q == 0) out[bcol*24 + tp] = yprev;
    }

    // ========= phase A: gates0 = Whh0*(h0hi+h0lo)  [stream whh0f (L2-warm) + h0] =========
    float h0n[2];
    {
      const f16* a0  = H0 + src*524288 + base_h;
      const f16* wfp = whh0f + (l << 3);
      f16x8 Wb0[2][4], Wb1[2][4], Bh[2][4], Bl[2][4];
      f32x4 acc0 = (f32x4){0,0,0,0}, acc1 = (f32x4){0,0,0,0};
#define LDA(B, CB) { _Pragma("unroll") for (int i = 0; i < 4; ++i){ const int c = (CB)+i; \
      Wb0[B][i] = *(const f16x8*)(wfp + ((2*c  ) << 9)); \
      Wb1[B][i] = *(const f16x8*)(wfp + ((2*c+1) << 9)); \
      Bh [B][i] = *(const f16x8*)(a0 + c*16384); \
      Bl [B][i] = *(const f16x8*)(a0 + c*16384 + 8); } }
#define MMA_A(B) { _Pragma("unroll") for (int i = 0; i < 4; ++i){ \
      acc0 = MFMA16(Wb0[B][i], Bh[B][i], acc0); acc0 = MFMA16(Wb0[B][i], Bl[B][i], acc0); \
      acc1 = MFMA16(Wb1[B][i], Bh[B][i], acc1); acc1 = MFMA16(Wb1[B][i], Bl[B][i], acc1); } }
      LDA(0, 0)
#pragma unroll
      for (int cb = 0; cb < 8; ++cb){
        if ((cb & 1) == 0){ if (cb < 7) LDA(1, (cb+1)*4) MMA_A(0) }
        else              { if (cb < 7) LDA(0, (cb+1)*4) MMA_A(1) }
      }
#undef LDA
#undef MMA_A
      float xb = (s < 84) ? seq[(s << 8) + bcol] : yprev;
      f32x4 at[2] = {acc0, acc1};
#pragma unroll
      for (int t = 0; t < 2; ++t){
        float pi = at[t][0] + bias0t[t][0] + wi0t[t][0]*xb;
        float pf = at[t][1] + bias0t[t][1] + wi0t[t][1]*xb;
        float pg = at[t][2] + bias0t[t][2] + wi0t[t][2]*xb;
        float po = at[t][3] + bias0t[t][3] + wi0t[t][3]*xb;
        c0[t]  = sigf(pf)*c0[t] + sigf(pi)*thf(pg);
        h0n[t] = sigf(po)*thf(c0[t]);
        f16 hi = (f16)h0n[t];
        f16 lo = (f16)(h0n[t] - (float)hi);
        stage[(lcol << 4) + q + t*4]     = hi;
        stage[(lcol << 4) + 8 + q + t*4] = lo;
      }
    }
    __syncthreads();
    if (tid < 256){
      u32x4 v = ((const u32x4*)stage)[tid];
      st_dwordx4_sc((char*)(H0 + dst*524288 + (hgrp << 12) + (bgrp << 11)) + tid*16, v);
    }
    ++ep; gbar(flags, gflags, ep, tid, blk, true);   // mid barrier WITH inv

    // ========= phase B: gates1 = Wih1*h0new + Whh1*h1  [LDS weights] =========
    float h1n[2];
    {
      const f16* b0 = H0 + dst*524288 + base_h;
      const f16* b1 = H1 + src*524288 + base_h;
      f16x8 X0h[2][4], X0l[2][4], X1h[2][4], X1l[2][4];
      f32x4 acc0 = (f32x4){0,0,0,0}, acc1 = (f32x4){0,0,0,0};
#define LDB(B, CB) { _Pragma("unroll") for (int i = 0; i < 4; ++i){ const int c = (CB)+i; \
      X0h[B][i] = *(const f16x8*)(b0 + c*16384); \
      X0l[B][i] = *(const f16x8*)(b0 + c*16384 + 8); \
      X1h[B][i] = *(const f16x8*)(b1 + c*16384); \
      X1l[B][i] = *(const f16x8*)(b1 + c*16384 + 8); } }
#define MMA_B(B, CB) { _Pragma("unroll") for (int i = 0; i < 4; ++i){ const int c = (CB)+i; \
      f16x8 wa0 = *(const f16x8*)(lds + ((2*c  ) << 9) + (l << 3)); \
      f16x8 wa1 = *(const f16x8*)(lds + ((2*c+1) << 9) + (l << 3)); \
      f16x8 wb0 = *(const f16x8*)(lds + 32768 + ((2*c  ) << 9) + (l << 3)); \
      f16x8 wb1 = *(const f16x8*)(lds + 32768 + ((2*c+1) << 9) + (l << 3)); \
      acc0 = MFMA16(wa0, X0h[B][i], acc0); acc0 = MFMA16(wa0, X0l[B][i], acc0); \
      acc0 = MFMA16(wb0, X1h[B][i], acc0); acc0 = MFMA16(wb0, X1l[B][i], acc0); \
      acc1 = MFMA16(wa1, X0h[B][i], acc1); acc1 = MFMA16(wa1, X0l[B][i], acc1); \
      acc1 = MFMA16(wb1, X1h[B][i], acc1); acc1 = MFMA16(wb1, X1l[B][i], acc1); } }
      LDB(0, 0)
#pragma unroll
      for (int cb = 0; cb < 8; ++cb){
        if ((cb & 1) == 0){ if (cb < 7) LDB(1, (cb+1)*4) MMA_B(0, cb*4) }
        else              { if (cb < 7) LDB(0, (cb+1)*4) MMA_B(1, cb*4) }
      }
#undef LDB
#undef MMA_B
      f32x4 at[2] = {acc0, acc1};
#pragma unroll
      for (int t = 0; t < 2; ++t){
        float pi = at[t][0] + bias1t[t][0];
        float pf = at[t][1] + bias1t[t][1];
        float pg = at[t][2] + bias1t[t][2];
        float po = at[t][3] + bias1t[t][3];
        c1[t]  = sigf(pf)*c1[t] + sigf(pi)*thf(pg);
        h1n[t] = sigf(po)*thf(c1[t]);
        f16 hi = (f16)h1n[t];
        f16 lo = (f16)(h1n[t] - (float)hi);
        stage[(lcol << 4) + q + t*4]     = hi;
        stage[(lcol << 4) + 8 + q + t*4] = lo;
      }
    }
    __syncthreads();
    if (tid < 256){
      u32x4 v = ((const u32x4*)stage)[tid];
      st_dwordx4_sc((char*)(H1 + dst*524288 + (hgrp << 12) + (bgrp << 11)) + tid*16, v);
    }
    __syncthreads();   // protect stage from next phase-A overwrite

    // ---- fc partials with exact JAX dropout (tau = s-83) ----
    if (s >= 83){
      const int tau = s - 83;
      uint2 fk = tf2x32(0u, 42u, 0u, (unsigned)tau);
      unsigned n0 = ((unsigned)bcol << 10) + (unsigned)(j0 + q);
      unsigned n1 = n0 + 4u;
      float v = (drop_keep(fk, n0) ? h1n[0]*fcw0 : 0.f)
              + (drop_keep(fk, n1) ? h1n[1]*fcw1 : 0.f);
      v += __shfl_xor(v, 16, 64);
      v += __shfl_xor(v, 32, 64);
      if (q == 0) atomicAdd(y_acc + (tau << 8) + bcol, v);
      ++ep; gbar(flags, gflags, ep, tid, blk, false);  // end barrier, NO inv
      // (audited: y_acc crosses via sc-load; h0/h1 re-guarded by next mid inv;
      //  bonus: whh0f stays L2-warm for next phase A)
    }
  }

  // tail: y_23 (LLC-coherent read)
  if (hgrp == 0 && q == 0)
    out[bcol*24 + 23] = fcb + __uint_as_float(ld_dword_sc(y_acc + (23 << 8) + bcol));
}

extern "C" void kernel_launch(void* const* d_in, const int* in_sizes, int n_in,
                              void* d_out, int out_size, void* d_ws, size_t ws_size,
                              hipStream_t stream)
{
  const float* x    = (const float*)d_in[0];
  const float* cw   = (const float*)d_in[1];
  const float* cb   = (const float*)d_in[2];
  const float* Wih0 = (const float*)d_in[3];
  const float* Whh0 = (const float*)d_in[4];
  const float* bih0 = (const float*)d_in[5];
  const float* bhh0 = (const float*)d_in[6];
  const float* Wih1 = (const float*)d_in[7];
  const float* Whh1 = (const float*)d_in[8];
  const float* bih1 = (const float*)d_in[9];
  const float* bhh1 = (const float*)d_in[10];
  const float* fc_w = (const float*)d_in[11];
  const float* fc_b = (const float*)d_in[12];
  float* out = (float*)d_out;
  char*  ws  = (char*)d_ws;

  hipLaunchKernelGGL(k_init, dim3(1040), dim3(256), 0, stream,
                     (uint4*)(ws + H0_OFF), (uint4*)(ws + YACC_OFF), (uint4*)(ws + FLAG_OFF));
  hipLaunchKernelGGL(k_seq,  dim3(84), dim3(256), 0, stream, x, cw, cb, (float*)(ws + SEQ_OFF));
  hipLaunchKernelGGL(k_wpack, dim3(128), dim3(512), 0, stream, Whh0, (f16*)(ws + WHH0F_OFF));
  hipLaunchKernelGGL(k_main, dim3(256), dim3(512), 135168, stream,
                     Wih0, Whh0, bih0, bhh0, Wih1, Whh1, bih1, bhh1,
                     fc_w, fc_b, ws, out);
}

// Round 14
// 4116.438 us; speedup vs baseline: 1.4214x; 1.0691x over previous
//
#include <hip/hip_runtime.h>
#include <stdint.h>

typedef _Float16 f16;
typedef f16  f16x8 __attribute__((ext_vector_type(8)));
typedef float f32x4 __attribute__((ext_vector_type(4)));
typedef unsigned u32x4 __attribute__((ext_vector_type(4)));

// ---------------- ws layout (byte offsets) ----------------
// H0/H1: 2 bufs x [k/8][b][hi8|lo8] f16 (1 MB per buf)
// WHH0F: fp16 MFMA A-frags of Whh0, [hgrp128][frag64][lane64][8] = 8 MB
// SEQ [84][256] f32 | YACC [24][256] f32 | FLAG 2 halves x (128+8) x 128B
#define H0_OFF    0u
#define H1_OFF    2097152u
#define WHH0F_OFF 4194304u
#define SEQ_OFF   12582912u
#define YACC_OFF  12668928u
#define FLAG_OFF  12693504u

__device__ __forceinline__ unsigned rotl32(unsigned x, int d){ return (x<<d)|(x>>(32-d)); }

// Threefry-2x32, 20 rounds, exactly JAX's key schedule. (bit-exact, proven R1-R13)
__device__ __forceinline__ uint2 tf2x32(unsigned k0, unsigned k1, unsigned x0, unsigned x1){
  unsigned kx = k0 ^ k1 ^ 0x1BD11BDAu;
  x0 += k0; x1 += k1;
#define TFR(r) { x0 += x1; x1 = rotl32(x1,(r)); x1 ^= x0; }
  TFR(13) TFR(15) TFR(26) TFR(6)  x0 += k1; x1 += kx + 1u;
  TFR(17) TFR(29) TFR(16) TFR(24) x0 += kx; x1 += k0 + 2u;
  TFR(13) TFR(15) TFR(26) TFR(6)  x0 += k0; x1 += k1 + 3u;
  TFR(17) TFR(29) TFR(16) TFR(24) x0 += k1; x1 += kx + 4u;
  TFR(13) TFR(15) TFR(26) TFR(6)  x0 += kx; x1 += k0 + 5u;
#undef TFR
  return make_uint2(x0, x1);
}

__device__ __forceinline__ bool drop_keep(uint2 fk, unsigned n){
  uint2 o = tf2x32(fk.x, fk.y, 0u, n);
  unsigned bits = o.x ^ o.y;
  float u = __uint_as_float((bits >> 9) | 0x3f800000u) - 1.0f;
  return u < 0.8f;
}

__device__ __forceinline__ float sigf(float x){ return 1.0f/(1.0f + __expf(-x)); }
__device__ __forceinline__ float thf(float x){ return 1.0f - 2.0f/(__expf(2.0f*x) + 1.0f); }

// ---- LLC-coherent accessors for flags/scalars/publication (proven R4-R13) ----
__device__ __forceinline__ void st_dword_sc(void* p, unsigned v){
  asm volatile("global_store_dword %0, %1, off sc0 sc1" :: "v"(p), "v"(v) : "memory");
}
__device__ __forceinline__ void st_dwordx4_sc(void* p, u32x4 v){
  asm volatile("global_store_dwordx4 %0, %1, off sc0 sc1" :: "v"(p), "v"(v) : "memory");
}
__device__ __forceinline__ unsigned ld_dword_sc(const void* p){
  unsigned r;
  asm volatile("global_load_dword %0, %1, off sc0 sc1\n\ts_waitcnt vmcnt(0)"
               : "=v"(r) : "v"(p) : "memory");
  return r;
}

// Per-half 2-level tree barrier: 128 blocks, 8 leaders x 16 flags; inv optional.
// The two batch halves share NO data (h, y_acc, out all col-partitioned), so
// each half syncs independently -> half the population, decoupled skew.
__device__ __forceinline__ void gbar(unsigned* flagsH, unsigned* gflagsH, unsigned e,
                                     int tid, int lblk, bool inv){
  asm volatile("s_waitcnt vmcnt(0)" ::: "memory");
  __syncthreads();
  if (tid == 0) st_dword_sc(flagsH + lblk*32, e);
  if (lblk < 8){
    if (tid < 16){
      unsigned* f = flagsH + (lblk*16 + tid)*32;
      while (ld_dword_sc(f) < e) __builtin_amdgcn_s_sleep(1);
    }
    __syncthreads();
    if (tid == 0) st_dword_sc(gflagsH + lblk*32, e);
  }
  if (tid < 8){
    unsigned* f = gflagsH + tid*32;
    while (ld_dword_sc(f) < e) __builtin_amdgcn_s_sleep(1);
  }
  __syncthreads();
  if (inv) __builtin_amdgcn_fence(__ATOMIC_ACQUIRE, "agent");
  __builtin_amdgcn_sched_barrier(0);
}

// ---- prep: zero h buffers + y_acc + flags (both halves incl. group flags) ----
__global__ void k_init(uint4* __restrict__ hz, uint4* __restrict__ yz, uint4* __restrict__ fz){
  unsigned i = blockIdx.x*256u + threadIdx.x;
  if (i < 262144u){ hz[i] = uint4{0,0,0,0}; }
  else if (i < 263680u){ yz[i - 262144u] = uint4{0,0,0,0}; }
  else if (i < 265856u){ fz[i - 263680u] = uint4{0,0,0,0}; }
}

// ---- prep: conv1d(pad1,k3) + relu + maxpool2 -> seq[84][256] ----
__global__ void k_seq(const float* __restrict__ x, const float* __restrict__ cw,
                      const float* __restrict__ cb, float* __restrict__ seq){
  const int q = blockIdx.x;
  const int b = threadIdx.x;
  float best = -1e30f;
#pragma unroll
  for (int ssub = 0; ssub < 2; ++ssub){
    int p = 2*q + ssub;
    float acc = cb[0];
#pragma unroll
    for (int k = 0; k < 3; ++k){
      int t = p - 1 + k;
      if (t >= 0 && t < 168){
        const float* xp = x + ((size_t)b*192 + t)*8;
#pragma unroll
        for (int i = 0; i < 8; ++i) acc = fmaf(xp[i], cw[i*3 + k], acc);
      }
    }
    acc  = fmaxf(acc, 0.0f);
    best = fmaxf(best, acc);
  }
  seq[(q<<8) + b] = best;
}

// ---- prep: pack Whh0 (fp32 [4096][1024]) into fp16 MFMA A-frags per hgrp ----
__global__ void __launch_bounds__(512) k_wpack(const float* __restrict__ W, f16* __restrict__ dst){
  const int hgrp = blockIdx.x;       // 0..127
  const int tid = threadIdx.x;
  const int l   = tid & 63;
  const int w   = tid >> 6;          // 0..7
  const int j0  = hgrp << 3;
#pragma unroll
  for (int fi = 0; fi < 8; ++fi){
    const int f = (w << 3) + fi;     // 0..63
    const int c = f >> 1, T = f & 1;
    const int r = l & 15;
    const int u = (T << 2) + (r >> 2);
    const int g = r & 3;
    const float* src = W + (((size_t)((g << 10) + j0 + u)) << 10) + (c << 5) + ((l >> 4) << 3);
    float4 a = *(const float4*)src;
    float4 b = *(const float4*)(src + 4);
    f16x8 v;
    v[0]=(f16)a.x; v[1]=(f16)a.y; v[2]=(f16)a.z; v[3]=(f16)a.w;
    v[4]=(f16)b.x; v[5]=(f16)b.y; v[6]=(f16)b.z; v[7]=(f16)b.w;
    *(f16x8*)(dst + ((size_t)hgrp << 15) + (f << 9) + (l << 3)) = v;
  }
}

#define MFMA16(a,b,c) __builtin_amdgcn_mfma_f32_16x16x32_f16((a),(b),(c),0,0,0)

// ---- main: 256 blocks (128 hgrp x 2 bgrp) x 512 threads (8 col-group waves) ----
// LDS: Wih1 64KB | Whh1 64KB | h-stage 4KB | whh0f chunk dbuf 2x8KB = 148KB
__global__ void __launch_bounds__(512, 1) k_main(
    const float* __restrict__ Wih0, const float* __restrict__ Whh0,
    const float* __restrict__ bih0, const float* __restrict__ bhh0,
    const float* __restrict__ Wih1, const float* __restrict__ Whh1,
    const float* __restrict__ bih1, const float* __restrict__ bhh1,
    const float* __restrict__ fc_w, const float* __restrict__ fc_b,
    char* __restrict__ ws, float* __restrict__ out)
{
  extern __shared__ char smem_[];
  f16* lds = (f16*)smem_;          // halves: [0,32768) Wih1 frags | [32768,65536) Whh1 frags
  f16* stage  = lds + 65536;       // 2048 halves: [128 local cols][hi8|lo8]
  f16* wstage = lds + 67584;       // 8192 halves: 2 bufs x 4096 (whh0f chunk staging)

  const int tid  = threadIdx.x;
  const int blk  = blockIdx.x;
  const int hgrp = blk & 127;      // hidden units 8*hgrp..+7 (also: id within half)
  const int bgrp = blk >> 7;       // batch cols bgrp*128..+127
  const int j0   = hgrp << 3;
  const int l    = tid & 63;
  const int w8   = tid >> 6;       // wave 0..7, local cols w8*16..+16
  const int q    = l >> 4;
  const int c16  = l & 15;
  const int lcol = (w8 << 4) + c16;     // 0..127
  const int bcol = (bgrp << 7) + lcol;  // absolute batch col

  // ---- pack Wih1, Whh1 slices into LDS as MFMA A-frags (once) ----
  {
    const float* srcs[2] = {Wih1, Whh1};
#pragma unroll
    for (int m = 0; m < 2; ++m){
#pragma unroll
      for (int fi = 0; fi < 8; ++fi){
        const int f = (w8 << 3) + fi;
        const int c = f >> 1, T = f & 1;
        const int r = c16;
        const int uu = (T << 2) + (r >> 2);
        const int g = r & 3;
        const float* src = srcs[m] + (((size_t)((g << 10) + j0 + uu)) << 10) + (c << 5) + (q << 3);
        float4 a = *(const float4*)src;
        float4 b = *(const float4*)(src + 4);
        f16x8 v;
        v[0]=(f16)a.x; v[1]=(f16)a.y; v[2]=(f16)a.z; v[3]=(f16)a.w;
        v[4]=(f16)b.x; v[5]=(f16)b.y; v[6]=(f16)b.z; v[7]=(f16)b.w;
        *(f16x8*)(lds + m*32768 + (f << 9) + (l << 3)) = v;
      }
    }
  }
  __syncthreads();

  // ---- per-lane constants (units q and q+4) ----
  float bias0t[2][4], bias1t[2][4], wi0t[2][4];
#pragma unroll
  for (int t = 0; t < 2; ++t){
    const int uu = j0 + q + t*4;
#pragma unroll
    for (int g = 0; g < 4; ++g){
      int row = (g << 10) + uu;
      bias0t[t][g] = bih0[row] + bhh0[row];
      bias1t[t][g] = bih1[row] + bhh1[row];
      wi0t[t][g]   = Wih0[row];
    }
  }
  const float fcw0 = fc_w[j0 + q] * 1.25f;
  const float fcw1 = fc_w[j0 + q + 4] * 1.25f;
  const float fcb  = fc_b[0];

  const int base_h = (q << 12) + (bcol << 4);   // per-lane B-frag offset (halves)

  f16* H0 = (f16*)(ws + H0_OFF);   // per-buf 524288 halves
  f16* H1 = (f16*)(ws + H1_OFF);
  const f16* whh0f = (const f16*)(ws + WHH0F_OFF) + ((size_t)hgrp << 15);
  const float* seq = (const float*)(ws + SEQ_OFF);
  float* y_acc = (float*)(ws + YACC_OFF);
  unsigned* flagsH  = (unsigned*)(ws + FLAG_OFF) + bgrp*4352;  // 128 flags + 8 gflags per half
  unsigned* gflagsH = flagsH + 128*32;

  float c0[2] = {0,0}, c1[2] = {0,0};
  float yprev = 0.f;
  unsigned ep = 0;

#pragma unroll 1
  for (int s = 0; s < 107; ++s){
    const int src = s & 1, dst = src ^ 1;

    if (s >= 84){
      const int tp = s - 84;
      // y_acc crosses the (inv-free) end barrier -> LLC-coherent read
      yprev = fcb + __uint_as_float(ld_dword_sc(y_acc + (tp << 8) + bcol));
      if (hgrp == 0 && q == 0) out[bcol*24 + tp] = yprev;
    }

    // ========= phase A: gates0 = Whh0*(h0hi+h0lo) =========
    // whh0f LDS-staged in 8x8KB chunks (64KB/block once, vs 8x redundant per-wave)
    float h0n[2];
    {
      const f16* a0 = H0 + src*524288 + base_h;
      f16x8 Bh[2][4], Bl[2][4];
      f32x4 acc0 = (f32x4){0,0,0,0}, acc1 = (f32x4){0,0,0,0};
      // stage chunk 0 (all 512 threads, 16B each)
      {
        u32x4 w0 = *(const u32x4*)(whh0f + (tid << 3));
        *(u32x4*)(wstage + (tid << 3)) = w0;
      }
      __syncthreads();
      u32x4 wreg = *(const u32x4*)(whh0f + 4096 + (tid << 3));   // chunk 1 in flight
#define LDH(B, C0) { _Pragma("unroll") for (int i = 0; i < 4; ++i){ const int c = (C0)+i; \
      Bh[B][i] = *(const f16x8*)(a0 + c*16384); \
      Bl[B][i] = *(const f16x8*)(a0 + c*16384 + 8); } }
#define MMW(B, CH) { const f16* wsb = wstage + (((CH)&1) << 12) + (l << 3); \
      _Pragma("unroll") for (int i = 0; i < 4; ++i){ \
      f16x8 wf0 = *(const f16x8*)(wsb + ((2*i  ) << 9)); \
      f16x8 wf1 = *(const f16x8*)(wsb + ((2*i+1) << 9)); \
      acc0 = MFMA16(wf0, Bh[B][i], acc0); acc0 = MFMA16(wf0, Bl[B][i], acc0); \
      acc1 = MFMA16(wf1, Bh[B][i], acc1); acc1 = MFMA16(wf1, Bl[B][i], acc1); } }
      LDH(0, 0) LDH(1, 4)
#pragma unroll
      for (int ch = 0; ch < 8; ++ch){
        MMW(ch&1, ch)
        if (ch < 6) LDH(ch&1, (ch+2)*4)
        if (ch < 7){
          *(u32x4*)(wstage + (((ch+1)&1) << 12) + (tid << 3)) = wreg;   // publish chunk ch+1
          __syncthreads();
          if (ch < 6) wreg = *(const u32x4*)(whh0f + ((size_t)(ch+2) << 12) + (tid << 3));
        }
      }
#undef LDH
#undef MMW
      float xb = (s < 84) ? seq[(s << 8) + bcol] : yprev;
      f32x4 at[2] = {acc0, acc1};
#pragma unroll
      for (int t = 0; t < 2; ++t){
        float pi = at[t][0] + bias0t[t][0] + wi0t[t][0]*xb;
        float pf = at[t][1] + bias0t[t][1] + wi0t[t][1]*xb;
        float pg = at[t][2] + bias0t[t][2] + wi0t[t][2]*xb;
        float po = at[t][3] + bias0t[t][3] + wi0t[t][3]*xb;
        c0[t]  = sigf(pf)*c0[t] + sigf(pi)*thf(pg);
        h0n[t] = sigf(po)*thf(c0[t]);
        f16 hi = (f16)h0n[t];
        f16 lo = (f16)(h0n[t] - (float)hi);
        stage[(lcol << 4) + q + t*4]     = hi;
        stage[(lcol << 4) + 8 + q + t*4] = lo;
      }
    }
    __syncthreads();
    if (tid < 256){
      u32x4 v = ((const u32x4*)stage)[tid];
      st_dwordx4_sc((char*)(H0 + dst*524288 + (hgrp << 12) + (bgrp << 11)) + tid*16, v);
    }
    ++ep; gbar(flagsH, gflagsH, ep, tid, hgrp, true);   // mid barrier WITH inv

    // ========= phase B: gates1 = Wih1*h0new + Whh1*h1  [LDS weights] =========
    float h1n[2];
    {
      const f16* b0 = H0 + dst*524288 + base_h;
      const f16* b1 = H1 + src*524288 + base_h;
      f16x8 X0h[2][4], X0l[2][4], X1h[2][4], X1l[2][4];
      f32x4 acc0 = (f32x4){0,0,0,0}, acc1 = (f32x4){0,0,0,0};
#define LDB(B, CB) { _Pragma("unroll") for (int i = 0; i < 4; ++i){ const int c = (CB)+i; \
      X0h[B][i] = *(const f16x8*)(b0 + c*16384); \
      X0l[B][i] = *(const f16x8*)(b0 + c*16384 + 8); \
      X1h[B][i] = *(const f16x8*)(b1 + c*16384); \
      X1l[B][i] = *(const f16x8*)(b1 + c*16384 + 8); } }
#define MMA_B(B, CB) { _Pragma("unroll") for (int i = 0; i < 4; ++i){ const int c = (CB)+i; \
      f16x8 wa0 = *(const f16x8*)(lds + ((2*c  ) << 9) + (l << 3)); \
      f16x8 wa1 = *(const f16x8*)(lds + ((2*c+1) << 9) + (l << 3)); \
      f16x8 wb0 = *(const f16x8*)(lds + 32768 + ((2*c  ) << 9) + (l << 3)); \
      f16x8 wb1 = *(const f16x8*)(lds + 32768 + ((2*c+1) << 9) + (l << 3)); \
      acc0 = MFMA16(wa0, X0h[B][i], acc0); acc0 = MFMA16(wa0, X0l[B][i], acc0); \
      acc0 = MFMA16(wb0, X1h[B][i], acc0); acc0 = MFMA16(wb0, X1l[B][i], acc0); \
      acc1 = MFMA16(wa1, X0h[B][i], acc1); acc1 = MFMA16(wa1, X0l[B][i], acc1); \
      acc1 = MFMA16(wb1, X1h[B][i], acc1); acc1 = MFMA16(wb1, X1l[B][i], acc1); } }
      LDB(0, 0)
#pragma unroll
      for (int cb = 0; cb < 8; ++cb){
        if ((cb & 1) == 0){ if (cb < 7) LDB(1, (cb+1)*4) MMA_B(0, cb*4) }
        else              { if (cb < 7) LDB(0, (cb+1)*4) MMA_B(1, cb*4) }
      }
#undef LDB
#undef MMA_B
      f32x4 at[2] = {acc0, acc1};
#pragma unroll
      for (int t = 0; t < 2; ++t){
        float pi = at[t][0] + bias1t[t][0];
        float pf = at[t][1] + bias1t[t][1];
        float pg = at[t][2] + bias1t[t][2];
        float po = at[t][3] + bias1t[t][3];
        c1[t]  = sigf(pf)*c1[t] + sigf(pi)*thf(pg);
        h1n[t] = sigf(po)*thf(c1[t]);
        f16 hi = (f16)h1n[t];
        f16 lo = (f16)(h1n[t] - (float)hi);
        stage[(lcol << 4) + q + t*4]     = hi;
        stage[(lcol << 4) + 8 + q + t*4] = lo;
      }
    }
    __syncthreads();
    if (tid < 256){
      u32x4 v = ((const u32x4*)stage)[tid];
      st_dwordx4_sc((char*)(H1 + dst*524288 + (hgrp << 12) + (bgrp << 11)) + tid*16, v);
    }
    __syncthreads();   // protect stage from next phase-A overwrite

    // ---- fc partials with exact JAX dropout (tau = s-83) ----
    if (s >= 83){
      const int tau = s - 83;
      uint2 fk = tf2x32(0u, 42u, 0u, (unsigned)tau);
      unsigned n0 = ((unsigned)bcol << 10) + (unsigned)(j0 + q);
      unsigned n1 = n0 + 4u;
      float v = (drop_keep(fk, n0) ? h1n[0]*fcw0 : 0.f)
              + (drop_keep(fk, n1) ? h1n[1]*fcw1 : 0.f);
      v += __shfl_xor(v, 16, 64);
      v += __shfl_xor(v, 32, 64);
      if (q == 0) atomicAdd(y_acc + (tau << 8) + bcol, v);
      ++ep; gbar(flagsH, gflagsH, ep, tid, hgrp, false);  // end barrier, NO inv
      // (audited: y_acc crosses via sc-load; h0/h1 re-guarded by next mid inv)
    }
  }

  // tail: y_23 (LLC-coherent read)
  if (hgrp == 0 && q == 0)
    out[bcol*24 + 23] = fcb + __uint_as_float(ld_dword_sc(y_acc + (23 << 8) + bcol));
}

extern "C" void kernel_launch(void* const* d_in, const int* in_sizes, int n_in,
                              void* d_out, int out_size, void* d_ws, size_t ws_size,
                              hipStream_t stream)
{
  const float* x    = (const float*)d_in[0];
  const float* cw   = (const float*)d_in[1];
  const float* cb   = (const float*)d_in[2];
  const float* Wih0 = (const float*)d_in[3];
  const float* Whh0 = (const float*)d_in[4];
  const float* bih0 = (const float*)d_in[5];
  const float* bhh0 = (const float*)d_in[6];
  const float* Wih1 = (const float*)d_in[7];
  const float* Whh1 = (const float*)d_in[8];
  const float* bih1 = (const float*)d_in[9];
  const float* bhh1 = (const float*)d_in[10];
  const float* fc_w = (const float*)d_in[11];
  const float* fc_b = (const float*)d_in[12];
  float* out = (float*)d_out;
  char*  ws  = (char*)d_ws;

  hipLaunchKernelGGL(k_init, dim3(1040), dim3(256), 0, stream,
                     (uint4*)(ws + H0_OFF), (uint4*)(ws + YACC_OFF), (uint4*)(ws + FLAG_OFF));
  hipLaunchKernelGGL(k_seq,  dim3(84), dim3(256), 0, stream, x, cw, cb, (float*)(ws + SEQ_OFF));
  hipLaunchKernelGGL(k_wpack, dim3(128), dim3(512), 0, stream, Whh0, (f16*)(ws + WHH0F_OFF));
  hipLaunchKernelGGL(k_main, dim3(256), dim3(512), 151552, stream,
                     Wih0, Whh0, bih0, bhh0, Wih1, Whh1, bih1, bhh1,
                     fc_w, fc_b, ws, out);
}

// Round 15
// 4031.145 us; speedup vs baseline: 1.4515x; 1.0212x over previous
//
#include <hip/hip_runtime.h>
#include <stdint.h>

typedef _Float16 f16;
typedef f16  f16x8 __attribute__((ext_vector_type(8)));
typedef float f32x4 __attribute__((ext_vector_type(4)));
typedef unsigned u32x4 __attribute__((ext_vector_type(4)));

// ---------------- ws layout (byte offsets) ----------------
// H0/H1: 2 bufs x [k/8][b][hi8|lo8] f16 (1 MB per buf)
// WHH0F: fp16 MFMA A-frags of Whh0, [hgrp128][frag64][lane64][8] = 8 MB
// SEQ [84][256] f32 | YACC [24][256] f32 | FLAG 2 halves x (128+8) x 128B
#define H0_OFF    0u
#define H1_OFF    2097152u
#define WHH0F_OFF 4194304u
#define SEQ_OFF   12582912u
#define YACC_OFF  12668928u
#define FLAG_OFF  12693504u

__device__ __forceinline__ unsigned rotl32(unsigned x, int d){ return (x<<d)|(x>>(32-d)); }

// Threefry-2x32, 20 rounds, exactly JAX's key schedule. (bit-exact, proven R1-R14)
__device__ __forceinline__ uint2 tf2x32(unsigned k0, unsigned k1, unsigned x0, unsigned x1){
  unsigned kx = k0 ^ k1 ^ 0x1BD11BDAu;
  x0 += k0; x1 += k1;
#define TFR(r) { x0 += x1; x1 = rotl32(x1,(r)); x1 ^= x0; }
  TFR(13) TFR(15) TFR(26) TFR(6)  x0 += k1; x1 += kx + 1u;
  TFR(17) TFR(29) TFR(16) TFR(24) x0 += kx; x1 += k0 + 2u;
  TFR(13) TFR(15) TFR(26) TFR(6)  x0 += k0; x1 += k1 + 3u;
  TFR(17) TFR(29) TFR(16) TFR(24) x0 += k1; x1 += kx + 4u;
  TFR(13) TFR(15) TFR(26) TFR(6)  x0 += kx; x1 += k0 + 5u;
#undef TFR
  return make_uint2(x0, x1);
}

__device__ __forceinline__ bool drop_keep(uint2 fk, unsigned n){
  uint2 o = tf2x32(fk.x, fk.y, 0u, n);
  unsigned bits = o.x ^ o.y;
  float u = __uint_as_float((bits >> 9) | 0x3f800000u) - 1.0f;
  return u < 0.8f;
}

__device__ __forceinline__ float sigf(float x){ return 1.0f/(1.0f + __expf(-x)); }
__device__ __forceinline__ float thf(float x){ return 1.0f - 2.0f/(__expf(2.0f*x) + 1.0f); }

// ---- LLC-coherent accessors for flags/scalars/publication (proven R4-R14) ----
__device__ __forceinline__ void st_dword_sc(void* p, unsigned v){
  asm volatile("global_store_dword %0, %1, off sc0 sc1" :: "v"(p), "v"(v) : "memory");
}
__device__ __forceinline__ void st_dwordx4_sc(void* p, u32x4 v){
  asm volatile("global_store_dwordx4 %0, %1, off sc0 sc1" :: "v"(p), "v"(v) : "memory");
}
__device__ __forceinline__ unsigned ld_dword_sc(const void* p){
  unsigned r;
  asm volatile("global_load_dword %0, %1, off sc0 sc1\n\ts_waitcnt vmcnt(0)"
               : "=v"(r) : "v"(p) : "memory");
  return r;
}

// Per-half 2-level tree barrier: 128 blocks, 8 leaders x 16 flags; inv optional.
__device__ __forceinline__ void gbar(unsigned* flagsH, unsigned* gflagsH, unsigned e,
                                     int tid, int lblk, bool inv){
  asm volatile("s_waitcnt vmcnt(0)" ::: "memory");
  __syncthreads();
  if (tid == 0) st_dword_sc(flagsH + lblk*32, e);
  if (lblk < 8){
    if (tid < 16){
      unsigned* f = flagsH + (lblk*16 + tid)*32;
      while (ld_dword_sc(f) < e) __builtin_amdgcn_s_sleep(1);
    }
    __syncthreads();
    if (tid == 0) st_dword_sc(gflagsH + lblk*32, e);
  }
  if (tid < 8){
    unsigned* f = gflagsH + tid*32;
    while (ld_dword_sc(f) < e) __builtin_amdgcn_s_sleep(1);
  }
  __syncthreads();
  if (inv) __builtin_amdgcn_fence(__ATOMIC_ACQUIRE, "agent");
  __builtin_amdgcn_sched_barrier(0);
}

// ---- prep: zero h buffers + y_acc + flags (both halves incl. group flags) ----
__global__ void k_init(uint4* __restrict__ hz, uint4* __restrict__ yz, uint4* __restrict__ fz){
  unsigned i = blockIdx.x*256u + threadIdx.x;
  if (i < 262144u){ hz[i] = uint4{0,0,0,0}; }
  else if (i < 263680u){ yz[i - 262144u] = uint4{0,0,0,0}; }
  else if (i < 265856u){ fz[i - 263680u] = uint4{0,0,0,0}; }
}

// ---- prep: conv1d(pad1,k3) + relu + maxpool2 -> seq[84][256] ----
__global__ void k_seq(const float* __restrict__ x, const float* __restrict__ cw,
                      const float* __restrict__ cb, float* __restrict__ seq){
  const int q = blockIdx.x;
  const int b = threadIdx.x;
  float best = -1e30f;
#pragma unroll
  for (int ssub = 0; ssub < 2; ++ssub){
    int p = 2*q + ssub;
    float acc = cb[0];
#pragma unroll
    for (int k = 0; k < 3; ++k){
      int t = p - 1 + k;
      if (t >= 0 && t < 168){
        const float* xp = x + ((size_t)b*192 + t)*8;
#pragma unroll
        for (int i = 0; i < 8; ++i) acc = fmaf(xp[i], cw[i*3 + k], acc);
      }
    }
    acc  = fmaxf(acc, 0.0f);
    best = fmaxf(best, acc);
  }
  seq[(q<<8) + b] = best;
}

// ---- prep: pack Whh0 (fp32 [4096][1024]) into fp16 MFMA A-frags per hgrp ----
__global__ void __launch_bounds__(512) k_wpack(const float* __restrict__ W, f16* __restrict__ dst){
  const int hgrp = blockIdx.x;       // 0..127
  const int tid = threadIdx.x;
  const int l   = tid & 63;
  const int w   = tid >> 6;          // 0..7
  const int j0  = hgrp << 3;
#pragma unroll
  for (int fi = 0; fi < 8; ++fi){
    const int f = (w << 3) + fi;     // 0..63
    const int c = f >> 1, T = f & 1;
    const int r = l & 15;
    const int u = (T << 2) + (r >> 2);
    const int g = r & 3;
    const float* src = W + (((size_t)((g << 10) + j0 + u)) << 10) + (c << 5) + ((l >> 4) << 3);
    float4 a = *(const float4*)src;
    float4 b = *(const float4*)(src + 4);
    f16x8 v;
    v[0]=(f16)a.x; v[1]=(f16)a.y; v[2]=(f16)a.z; v[3]=(f16)a.w;
    v[4]=(f16)b.x; v[5]=(f16)b.y; v[6]=(f16)b.z; v[7]=(f16)b.w;
    *(f16x8*)(dst + ((size_t)hgrp << 15) + (f << 9) + (l << 3)) = v;
  }
}

#define MFMA16(a,b,c) __builtin_amdgcn_mfma_f32_16x16x32_f16((a),(b),(c),0,0,0)

// ---- main: 256 blocks (128 hgrp x 2 bgrp) x 512 threads (8 col-group waves) ----
// LDS: Wih1 64KB | Whh1 64KB | h-stage 4KB | whh0f chunk dbuf 2x8KB = 148KB
__global__ void __launch_bounds__(512, 1) k_main(
    const float* __restrict__ Wih0, const float* __restrict__ Whh0,
    const float* __restrict__ bih0, const float* __restrict__ bhh0,
    const float* __restrict__ Wih1, const float* __restrict__ Whh1,
    const float* __restrict__ bih1, const float* __restrict__ bhh1,
    const float* __restrict__ fc_w, const float* __restrict__ fc_b,
    char* __restrict__ ws, float* __restrict__ out)
{
  extern __shared__ char smem_[];
  f16* lds = (f16*)smem_;          // halves: [0,32768) Wih1 frags | [32768,65536) Whh1 frags
  f16* stage  = lds + 65536;       // 2048 halves: [128 local cols][hi8|lo8]
  f16* wstage = lds + 67584;       // 8192 halves: 2 bufs x 4096 (whh0f chunk staging)

  const int tid  = threadIdx.x;
  const int blk  = blockIdx.x;
  const int hgrp = blk & 127;      // hidden units 8*hgrp..+7 (also: id within half)
  const int bgrp = blk >> 7;       // batch cols bgrp*128..+127
  const int j0   = hgrp << 3;
  const int l    = tid & 63;
  const int w8   = tid >> 6;       // wave 0..7, local cols w8*16..+16
  const int q    = l >> 4;
  const int c16  = l & 15;
  const int lcol = (w8 << 4) + c16;     // 0..127
  const int bcol = (bgrp << 7) + lcol;  // absolute batch col

  // ---- pack Wih1, Whh1 slices into LDS as MFMA A-frags (once) ----
  {
    const float* srcs[2] = {Wih1, Whh1};
#pragma unroll
    for (int m = 0; m < 2; ++m){
#pragma unroll
      for (int fi = 0; fi < 8; ++fi){
        const int f = (w8 << 3) + fi;
        const int c = f >> 1, T = f & 1;
        const int r = c16;
        const int uu = (T << 2) + (r >> 2);
        const int g = r & 3;
        const float* src = srcs[m] + (((size_t)((g << 10) + j0 + uu)) << 10) + (c << 5) + (q << 3);
        float4 a = *(const float4*)src;
        float4 b = *(const float4*)(src + 4);
        f16x8 v;
        v[0]=(f16)a.x; v[1]=(f16)a.y; v[2]=(f16)a.z; v[3]=(f16)a.w;
        v[4]=(f16)b.x; v[5]=(f16)b.y; v[6]=(f16)b.z; v[7]=(f16)b.w;
        *(f16x8*)(lds + m*32768 + (f << 9) + (l << 3)) = v;
      }
    }
  }
  __syncthreads();

  // ---- per-lane constants (units q and q+4) ----
  float bias0t[2][4], bias1t[2][4], wi0t[2][4];
#pragma unroll
  for (int t = 0; t < 2; ++t){
    const int uu = j0 + q + t*4;
#pragma unroll
    for (int g = 0; g < 4; ++g){
      int row = (g << 10) + uu;
      bias0t[t][g] = bih0[row] + bhh0[row];
      bias1t[t][g] = bih1[row] + bhh1[row];
      wi0t[t][g]   = Wih0[row];
    }
  }
  const float fcw0 = fc_w[j0 + q] * 1.25f;
  const float fcw1 = fc_w[j0 + q + 4] * 1.25f;
  const float fcb  = fc_b[0];

  const int base_h = (q << 12) + (bcol << 4);   // per-lane B-frag offset (halves)

  f16* H0 = (f16*)(ws + H0_OFF);   // per-buf 524288 halves
  f16* H1 = (f16*)(ws + H1_OFF);
  const f16* whh0f = (const f16*)(ws + WHH0F_OFF) + ((size_t)hgrp << 15);
  const float* seq = (const float*)(ws + SEQ_OFF);
  float* y_acc = (float*)(ws + YACC_OFF);
  unsigned* flagsH  = (unsigned*)(ws + FLAG_OFF) + bgrp*4352;  // 128 flags + 8 gflags per half
  unsigned* gflagsH = flagsH + 128*32;

  float c0[2] = {0,0}, c1[2] = {0,0};
  float yprev = 0.f;
  unsigned ep = 0;

#pragma unroll 1
  for (int s = 0; s < 107; ++s){
    const int src = s & 1, dst = src ^ 1;

    if (s >= 84){
      const int tp = s - 84;
      // y_acc crosses the (inv-free) end barrier -> LLC-coherent read
      yprev = fcb + __uint_as_float(ld_dword_sc(y_acc + (tp << 8) + bcol));
      if (hgrp == 0 && q == 0) out[bcol*24 + tp] = yprev;
    }

    // ========= phase A: gates0 = Whh0*(h0hi+h0lo) =========
    // ALL 8 whh0f chunks preloaded to regs upfront (one LLC latency ramp, then
    // LDS publish+consume) -- replaces R14's 7-deep serialized chunk chain.
    float h0n[2];
    {
      const f16* a0 = H0 + src*524288 + base_h;
      f16x8 Bh[2][4], Bl[2][4];
      u32x4 wreg[8];
      f32x4 acc0 = (f32x4){0,0,0,0}, acc1 = (f32x4){0,0,0,0};
#pragma unroll
      for (int ch = 0; ch < 8; ++ch)
        wreg[ch] = *(const u32x4*)(whh0f + ((size_t)ch << 12) + (tid << 3));
      *(u32x4*)(wstage + (tid << 3)) = wreg[0];   // stage chunk 0
#define LDH(B, C0) { _Pragma("unroll") for (int i = 0; i < 4; ++i){ const int c = (C0)+i; \
      Bh[B][i] = *(const f16x8*)(a0 + c*16384); \
      Bl[B][i] = *(const f16x8*)(a0 + c*16384 + 8); } }
#define MMW(B, CH) { const f16* wsb = wstage + (((CH)&1) << 12) + (l << 3); \
      _Pragma("unroll") for (int i = 0; i < 4; ++i){ \
      f16x8 wf0 = *(const f16x8*)(wsb + ((2*i  ) << 9)); \
      f16x8 wf1 = *(const f16x8*)(wsb + ((2*i+1) << 9)); \
      acc0 = MFMA16(wf0, Bh[B][i], acc0); acc0 = MFMA16(wf0, Bl[B][i], acc0); \
      acc1 = MFMA16(wf1, Bh[B][i], acc1); acc1 = MFMA16(wf1, Bl[B][i], acc1); } }
      LDH(0, 0) LDH(1, 4)
      __syncthreads();
#pragma unroll
      for (int ch = 0; ch < 8; ++ch){
        if (ch < 7) *(u32x4*)(wstage + (((ch+1)&1) << 12) + (tid << 3)) = wreg[ch+1];
        MMW(ch&1, ch)
        if (ch < 6) LDH(ch&1, (ch+2)*4)
        if (ch < 7) __syncthreads();
      }
#undef LDH
#undef MMW
      float xb = (s < 84) ? seq[(s << 8) + bcol] : yprev;
      f32x4 at[2] = {acc0, acc1};
#pragma unroll
      for (int t = 0; t < 2; ++t){
        float pi = at[t][0] + bias0t[t][0] + wi0t[t][0]*xb;
        float pf = at[t][1] + bias0t[t][1] + wi0t[t][1]*xb;
        float pg = at[t][2] + bias0t[t][2] + wi0t[t][2]*xb;
        float po = at[t][3] + bias0t[t][3] + wi0t[t][3]*xb;
        c0[t]  = sigf(pf)*c0[t] + sigf(pi)*thf(pg);
        h0n[t] = sigf(po)*thf(c0[t]);
        f16 hi = (f16)h0n[t];
        f16 lo = (f16)(h0n[t] - (float)hi);
        stage[(lcol << 4) + q + t*4]     = hi;
        stage[(lcol << 4) + 8 + q + t*4] = lo;
      }
    }
    __syncthreads();
    if (tid < 256){
      u32x4 v = ((const u32x4*)stage)[tid];
      st_dwordx4_sc((char*)(H0 + dst*524288 + (hgrp << 12) + (bgrp << 11)) + tid*16, v);
    }
    ++ep; gbar(flagsH, gflagsH, ep, tid, hgrp, true);   // mid barrier WITH inv

    // ========= phase B: gates1 = Wih1*h0new + Whh1*h1  [LDS weights] =========
    float h1n[2];
    {
      const f16* b0 = H0 + dst*524288 + base_h;
      const f16* b1 = H1 + src*524288 + base_h;
      f16x8 X0h[2][4], X0l[2][4], X1h[2][4], X1l[2][4];
      f32x4 acc0 = (f32x4){0,0,0,0}, acc1 = (f32x4){0,0,0,0};
#define LDB(B, CB) { _Pragma("unroll") for (int i = 0; i < 4; ++i){ const int c = (CB)+i; \
      X0h[B][i] = *(const f16x8*)(b0 + c*16384); \
      X0l[B][i] = *(const f16x8*)(b0 + c*16384 + 8); \
      X1h[B][i] = *(const f16x8*)(b1 + c*16384); \
      X1l[B][i] = *(const f16x8*)(b1 + c*16384 + 8); } }
#define MMA_B(B, CB) { _Pragma("unroll") for (int i = 0; i < 4; ++i){ const int c = (CB)+i; \
      f16x8 wa0 = *(const f16x8*)(lds + ((2*c  ) << 9) + (l << 3)); \
      f16x8 wa1 = *(const f16x8*)(lds + ((2*c+1) << 9) + (l << 3)); \
      f16x8 wb0 = *(const f16x8*)(lds + 32768 + ((2*c  ) << 9) + (l << 3)); \
      f16x8 wb1 = *(const f16x8*)(lds + 32768 + ((2*c+1) << 9) + (l << 3)); \
      acc0 = MFMA16(wa0, X0h[B][i], acc0); acc0 = MFMA16(wa0, X0l[B][i], acc0); \
      acc0 = MFMA16(wb0, X1h[B][i], acc0); acc0 = MFMA16(wb0, X1l[B][i], acc0); \
      acc1 = MFMA16(wa1, X0h[B][i], acc1); acc1 = MFMA16(wa1, X0l[B][i], acc1); \
      acc1 = MFMA16(wb1, X1h[B][i], acc1); acc1 = MFMA16(wb1, X1l[B][i], acc1); } }
      LDB(0, 0)
#pragma unroll
      for (int cb = 0; cb < 8; ++cb){
        if ((cb & 1) == 0){ if (cb < 7) LDB(1, (cb+1)*4) MMA_B(0, cb*4) }
        else              { if (cb < 7) LDB(0, (cb+1)*4) MMA_B(1, cb*4) }
      }
#undef LDB
#undef MMA_B
      f32x4 at[2] = {acc0, acc1};
#pragma unroll
      for (int t = 0; t < 2; ++t){
        float pi = at[t][0] + bias1t[t][0];
        float pf = at[t][1] + bias1t[t][1];
        float pg = at[t][2] + bias1t[t][2];
        float po = at[t][3] + bias1t[t][3];
        c1[t]  = sigf(pf)*c1[t] + sigf(pi)*thf(pg);
        h1n[t] = sigf(po)*thf(c1[t]);
        f16 hi = (f16)h1n[t];
        f16 lo = (f16)(h1n[t] - (float)hi);
        stage[(lcol << 4) + q + t*4]     = hi;
        stage[(lcol << 4) + 8 + q + t*4] = lo;
      }
    }
    __syncthreads();
    if (tid < 256){
      u32x4 v = ((const u32x4*)stage)[tid];
      st_dwordx4_sc((char*)(H1 + dst*524288 + (hgrp << 12) + (bgrp << 11)) + tid*16, v);
    }
    __syncthreads();   // protect stage from next phase-A overwrite

    // ---- fc partials with exact JAX dropout (tau = s-83) ----
    if (s >= 83){
      const int tau = s - 83;
      uint2 fk = tf2x32(0u, 42u, 0u, (unsigned)tau);
      unsigned n0 = ((unsigned)bcol << 10) + (unsigned)(j0 + q);
      unsigned n1 = n0 + 4u;
      float v = (drop_keep(fk, n0) ? h1n[0]*fcw0 : 0.f)
              + (drop_keep(fk, n1) ? h1n[1]*fcw1 : 0.f);
      v += __shfl_xor(v, 16, 64);
      v += __shfl_xor(v, 32, 64);
      if (q == 0) atomicAdd(y_acc + (tau << 8) + bcol, v);
      ++ep; gbar(flagsH, gflagsH, ep, tid, hgrp, false);  // end barrier, NO inv
      // (audited: y_acc crosses via sc-load; h0/h1 re-guarded by next mid inv)
    }
  }

  // tail: y_23 (LLC-coherent read)
  if (hgrp == 0 && q == 0)
    out[bcol*24 + 23] = fcb + __uint_as_float(ld_dword_sc(y_acc + (23 << 8) + bcol));
}

extern "C" void kernel_launch(void* const* d_in, const int* in_sizes, int n_in,
                              void* d_out, int out_size, void* d_ws, size_t ws_size,
                              hipStream_t stream)
{
  const float* x    = (const float*)d_in[0];
  const float* cw   = (const float*)d_in[1];
  const float* cb   = (const float*)d_in[2];
  const float* Wih0 = (const float*)d_in[3];
  const float* Whh0 = (const float*)d_in[4];
  const float* bih0 = (const float*)d_in[5];
  const float* bhh0 = (const float*)d_in[6];
  const float* Wih1 = (const float*)d_in[7];
  const float* Whh1 = (const float*)d_in[8];
  const float* bih1 = (const float*)d_in[9];
  const float* bhh1 = (const float*)d_in[10];
  const float* fc_w = (const float*)d_in[11];
  const float* fc_b = (const float*)d_in[12];
  float* out = (float*)d_out;
  char*  ws  = (char*)d_ws;

  hipLaunchKernelGGL(k_init, dim3(1040), dim3(256), 0, stream,
                     (uint4*)(ws + H0_OFF), (uint4*)(ws + YACC_OFF), (uint4*)(ws + FLAG_OFF));
  hipLaunchKernelGGL(k_seq,  dim3(84), dim3(256), 0, stream, x, cw, cb, (float*)(ws + SEQ_OFF));
  hipLaunchKernelGGL(k_wpack, dim3(128), dim3(512), 0, stream, Whh0, (f16*)(ws + WHH0F_OFF));
  hipLaunchKernelGGL(k_main, dim3(256), dim3(512), 151552, stream,
                     Wih0, Whh0, bih0, bhh0, Wih1, Whh1, bih1, bhh1,
                     fc_w, fc_b, ws, out);
}

// Round 16
// 3007.237 us; speedup vs baseline: 1.9457x; 1.3405x over previous
//
#include <hip/hip_runtime.h>
#include <stdint.h>

typedef _Float16 f16;
typedef f16  f16x8 __attribute__((ext_vector_type(8)));
typedef float f32x4 __attribute__((ext_vector_type(4)));
typedef unsigned u32x4 __attribute__((ext_vector_type(4)));

// ---------------- ws layout (byte offsets) ----------------
// H0/H1: 2 bufs x [k/8][b][8] f16 (fp16-only h, 512KB per buf)
// WHH0F: fp16 MFMA A-frags of Whh0, [hgrp128][frag64][lane64][8] = 8 MB
// SEQ [84][256] f32 | YACC [24][256] f32 | FLAG 2 halves x (128+8) x 128B
#define H0_OFF    0u
#define H1_OFF    2097152u
#define WHH0F_OFF 4194304u
#define SEQ_OFF   12582912u
#define YACC_OFF  12668928u
#define FLAG_OFF  12693504u

__device__ __forceinline__ unsigned rotl32(unsigned x, int d){ return (x<<d)|(x>>(32-d)); }

// Threefry-2x32, 20 rounds, exactly JAX's key schedule. (bit-exact, proven R1-R15)
__device__ __forceinline__ uint2 tf2x32(unsigned k0, unsigned k1, unsigned x0, unsigned x1){
  unsigned kx = k0 ^ k1 ^ 0x1BD11BDAu;
  x0 += k0; x1 += k1;
#define TFR(r) { x0 += x1; x1 = rotl32(x1,(r)); x1 ^= x0; }
  TFR(13) TFR(15) TFR(26) TFR(6)  x0 += k1; x1 += kx + 1u;
  TFR(17) TFR(29) TFR(16) TFR(24) x0 += kx; x1 += k0 + 2u;
  TFR(13) TFR(15) TFR(26) TFR(6)  x0 += k0; x1 += k1 + 3u;
  TFR(17) TFR(29) TFR(16) TFR(24) x0 += k1; x1 += kx + 4u;
  TFR(13) TFR(15) TFR(26) TFR(6)  x0 += kx; x1 += k0 + 5u;
#undef TFR
  return make_uint2(x0, x1);
}

__device__ __forceinline__ bool drop_keep(uint2 fk, unsigned n){
  uint2 o = tf2x32(fk.x, fk.y, 0u, n);
  unsigned bits = o.x ^ o.y;
  float u = __uint_as_float((bits >> 9) | 0x3f800000u) - 1.0f;
  return u < 0.8f;
}

__device__ __forceinline__ float sigf(float x){ return 1.0f/(1.0f + __expf(-x)); }
__device__ __forceinline__ float thf(float x){ return 1.0f - 2.0f/(__expf(2.0f*x) + 1.0f); }

// ---- LLC-coherent accessors for flags/scalars/publication (proven R4-R15) ----
__device__ __forceinline__ void st_dword_sc(void* p, unsigned v){
  asm volatile("global_store_dword %0, %1, off sc0 sc1" :: "v"(p), "v"(v) : "memory");
}
__device__ __forceinline__ void st_dwordx4_sc(void* p, u32x4 v){
  asm volatile("global_store_dwordx4 %0, %1, off sc0 sc1" :: "v"(p), "v"(v) : "memory");
}
__device__ __forceinline__ unsigned ld_dword_sc(const void* p){
  unsigned r;
  asm volatile("global_load_dword %0, %1, off sc0 sc1\n\ts_waitcnt vmcnt(0)"
               : "=v"(r) : "v"(p) : "memory");
  return r;
}

// Per-half 2-level tree barrier: 128 blocks, 8 leaders x 16 flags; inv optional.
__device__ __forceinline__ void gbar(unsigned* flagsH, unsigned* gflagsH, unsigned e,
                                     int tid, int lblk, bool inv){
  asm volatile("s_waitcnt vmcnt(0)" ::: "memory");
  __syncthreads();
  if (tid == 0) st_dword_sc(flagsH + lblk*32, e);
  if (lblk < 8){
    if (tid < 16){
      unsigned* f = flagsH + (lblk*16 + tid)*32;
      while (ld_dword_sc(f) < e) __builtin_amdgcn_s_sleep(1);
    }
    __syncthreads();
    if (tid == 0) st_dword_sc(gflagsH + lblk*32, e);
  }
  if (tid < 8){
    unsigned* f = gflagsH + tid*32;
    while (ld_dword_sc(f) < e) __builtin_amdgcn_s_sleep(1);
  }
  __syncthreads();
  if (inv) __builtin_amdgcn_fence(__ATOMIC_ACQUIRE, "agent");
  __builtin_amdgcn_sched_barrier(0);
}

// ---- prep: zero h buffers + y_acc + flags (both halves incl. group flags) ----
__global__ void k_init(uint4* __restrict__ hz, uint4* __restrict__ yz, uint4* __restrict__ fz){
  unsigned i = blockIdx.x*256u + threadIdx.x;
  if (i < 262144u){ hz[i] = uint4{0,0,0,0}; }
  else if (i < 263680u){ yz[i - 262144u] = uint4{0,0,0,0}; }
  else if (i < 265856u){ fz[i - 263680u] = uint4{0,0,0,0}; }
}

// ---- prep: conv1d(pad1,k3) + relu + maxpool2 -> seq[84][256] ----
__global__ void k_seq(const float* __restrict__ x, const float* __restrict__ cw,
                      const float* __restrict__ cb, float* __restrict__ seq){
  const int q = blockIdx.x;
  const int b = threadIdx.x;
  float best = -1e30f;
#pragma unroll
  for (int ssub = 0; ssub < 2; ++ssub){
    int p = 2*q + ssub;
    float acc = cb[0];
#pragma unroll
    for (int k = 0; k < 3; ++k){
      int t = p - 1 + k;
      if (t >= 0 && t < 168){
        const float* xp = x + ((size_t)b*192 + t)*8;
#pragma unroll
        for (int i = 0; i < 8; ++i) acc = fmaf(xp[i], cw[i*3 + k], acc);
      }
    }
    acc  = fmaxf(acc, 0.0f);
    best = fmaxf(best, acc);
  }
  seq[(q<<8) + b] = best;
}

// ---- prep: pack Whh0 (fp32 [4096][1024]) into fp16 MFMA A-frags per hgrp ----
__global__ void __launch_bounds__(512) k_wpack(const float* __restrict__ W, f16* __restrict__ dst){
  const int hgrp = blockIdx.x;       // 0..127
  const int tid = threadIdx.x;
  const int l   = tid & 63;
  const int w   = tid >> 6;          // 0..7
  const int j0  = hgrp << 3;
#pragma unroll
  for (int fi = 0; fi < 8; ++fi){
    const int f = (w << 3) + fi;     // 0..63
    const int c = f >> 1, T = f & 1;
    const int r = l & 15;
    const int u = (T << 2) + (r >> 2);
    const int g = r & 3;
    const float* src = W + (((size_t)((g << 10) + j0 + u)) << 10) + (c << 5) + ((l >> 4) << 3);
    float4 a = *(const float4*)src;
    float4 b = *(const float4*)(src + 4);
    f16x8 v;
    v[0]=(f16)a.x; v[1]=(f16)a.y; v[2]=(f16)a.z; v[3]=(f16)a.w;
    v[4]=(f16)b.x; v[5]=(f16)b.y; v[6]=(f16)b.z; v[7]=(f16)b.w;
    *(f16x8*)(dst + ((size_t)hgrp << 15) + (f << 9) + (l << 3)) = v;
  }
}

#define MFMA16(a,b,c) __builtin_amdgcn_mfma_f32_16x16x32_f16((a),(b),(c),0,0,0)

// ---- main: 256 blocks (128 hgrp x 2 bgrp) x 512 threads (8 col-group waves) ----
// LDS: Wih1 64KB | Whh1 64KB | h-stage 2KB | whh0f chunk dbuf 2x8KB = 146KB
// whh0f held in 32 VGPRs for the whole kernel (weights are step-invariant).
__global__ void __launch_bounds__(512, 1) k_main(
    const float* __restrict__ Wih0, const float* __restrict__ Whh0,
    const float* __restrict__ bih0, const float* __restrict__ bhh0,
    const float* __restrict__ Wih1, const float* __restrict__ Whh1,
    const float* __restrict__ bih1, const float* __restrict__ bhh1,
    const float* __restrict__ fc_w, const float* __restrict__ fc_b,
    char* __restrict__ ws, float* __restrict__ out)
{
  extern __shared__ char smem_[];
  f16* lds = (f16*)smem_;          // halves: [0,32768) Wih1 frags | [32768,65536) Whh1 frags
  f16* stage  = lds + 65536;       // 1024 halves: [128 local cols][8 units]
  f16* wstage = lds + 66560;       // 8192 halves: 2 bufs x 4096 (whh0f chunk staging)

  const int tid  = threadIdx.x;
  const int blk  = blockIdx.x;
  const int hgrp = blk & 127;      // hidden units 8*hgrp..+7 (also kgroup id)
  const int bgrp = blk >> 7;       // batch cols bgrp*128..+127
  const int j0   = hgrp << 3;
  const int l    = tid & 63;
  const int w8   = tid >> 6;       // wave 0..7, local cols w8*16..+16
  const int q    = l >> 4;
  const int c16  = l & 15;
  const int lcol = (w8 << 4) + c16;     // 0..127
  const int bcol = (bgrp << 7) + lcol;  // absolute batch col

  // ---- pack Wih1, Whh1 slices into LDS as MFMA A-frags (once) ----
  {
    const float* srcs[2] = {Wih1, Whh1};
#pragma unroll
    for (int m = 0; m < 2; ++m){
#pragma unroll
      for (int fi = 0; fi < 8; ++fi){
        const int f = (w8 << 3) + fi;
        const int c = f >> 1, T = f & 1;
        const int r = c16;
        const int uu = (T << 2) + (r >> 2);
        const int g = r & 3;
        const float* src = srcs[m] + (((size_t)((g << 10) + j0 + uu)) << 10) + (c << 5) + (q << 3);
        float4 a = *(const float4*)src;
        float4 b = *(const float4*)(src + 4);
        f16x8 v;
        v[0]=(f16)a.x; v[1]=(f16)a.y; v[2]=(f16)a.z; v[3]=(f16)a.w;
        v[4]=(f16)b.x; v[5]=(f16)b.y; v[6]=(f16)b.z; v[7]=(f16)b.w;
        *(f16x8*)(lds + m*32768 + (f << 9) + (l << 3)) = v;
      }
    }
  }
  __syncthreads();

  // ---- per-lane constants (units q and q+4) ----
  float bias0t[2][4], bias1t[2][4], wi0t[2][4];
#pragma unroll
  for (int t = 0; t < 2; ++t){
    const int uu = j0 + q + t*4;
#pragma unroll
    for (int g = 0; g < 4; ++g){
      int row = (g << 10) + uu;
      bias0t[t][g] = bih0[row] + bhh0[row];
      bias1t[t][g] = bih1[row] + bhh1[row];
      wi0t[t][g]   = Wih0[row];
    }
  }
  const float fcw0 = fc_w[j0 + q] * 1.25f;
  const float fcw1 = fc_w[j0 + q + 4] * 1.25f;
  const float fcb  = fc_b[0];

  const int base_h = (q << 11) + (bcol << 3);   // per-lane B-frag offset (halves)

  f16* H0 = (f16*)(ws + H0_OFF);   // per-buf 262144 halves (fp16-only)
  f16* H1 = (f16*)(ws + H1_OFF);
  const f16* whh0f = (const f16*)(ws + WHH0F_OFF) + ((size_t)hgrp << 15);
  const float* seq = (const float*)(ws + SEQ_OFF);
  float* y_acc = (float*)(ws + YACC_OFF);
  unsigned* flagsH  = (unsigned*)(ws + FLAG_OFF) + bgrp*4352;
  unsigned* gflagsH = flagsH + 128*32;

  // ---- whh0f resident in registers for the whole kernel (8 x 16B/thread) ----
  u32x4 wreg[8];
#pragma unroll
  for (int ch = 0; ch < 8; ++ch)
    wreg[ch] = *(const u32x4*)(whh0f + ((size_t)ch << 12) + (tid << 3));

  // ---- prefetched phase-A h groups (rolling 2-group buffer, crosses barriers) ----
  f16x8 BhP[2][4];
  {
    const f16* a00 = H0 + base_h;      // src buf 0 (zeroed)
#pragma unroll
    for (int i = 0; i < 4; ++i){
      BhP[0][i] = *(const f16x8*)(a00 + i*8192);
      BhP[1][i] = *(const f16x8*)(a00 + (4+i)*8192);
    }
  }

  float c0[2] = {0,0}, c1[2] = {0,0};
  float yprev = 0.f;
  unsigned ep = 0;

#pragma unroll 1
  for (int s = 0; s < 107; ++s){
    const int src = s & 1, dst = src ^ 1;

    if (s >= 84){
      const int tp = s - 84;
      yprev = fcb + __uint_as_float(ld_dword_sc(y_acc + (tp << 8) + bcol));
      if (hgrp == 0 && q == 0) out[bcol*24 + tp] = yprev;
    }

    // ========= phase A: gates0 = Whh0*h0 (fp16 h, weights from regs via LDS) =========
    float h0n[2];
    {
      const f16* a0 = H0 + src*262144 + base_h;
      f32x4 acc0 = (f32x4){0,0,0,0}, acc1 = (f32x4){0,0,0,0};
      *(u32x4*)(wstage + (tid << 3)) = wreg[0];   // publish chunk 0 -> buf 0
      __syncthreads();
#define LDH(B, C0) { _Pragma("unroll") for (int i = 0; i < 4; ++i){ \
      BhP[B][i] = *(const f16x8*)(a0 + ((C0)+i)*8192); } }
#define MMW(B, CH) { const f16* wsb = wstage + (((CH)&1) << 12) + (l << 3); \
      _Pragma("unroll") for (int i = 0; i < 4; ++i){ \
      f16x8 wf0 = *(const f16x8*)(wsb + ((2*i  ) << 9)); \
      f16x8 wf1 = *(const f16x8*)(wsb + ((2*i+1) << 9)); \
      acc0 = MFMA16(wf0, BhP[B][i], acc0); \
      acc1 = MFMA16(wf1, BhP[B][i], acc1); } }
#pragma unroll
      for (int ch = 0; ch < 8; ++ch){
        if (ch < 7) *(u32x4*)(wstage + (((ch+1)&1) << 12) + (tid << 3)) = wreg[ch+1];
        MMW(ch&1, ch)
        if (ch < 6) LDH(ch&1, (ch+2)*4)
        if (ch < 7) __syncthreads();
      }
#undef LDH
#undef MMW
      float xb = (s < 84) ? seq[(s << 8) + bcol] : yprev;
      f32x4 at[2] = {acc0, acc1};
#pragma unroll
      for (int t = 0; t < 2; ++t){
        float pi = at[t][0] + bias0t[t][0] + wi0t[t][0]*xb;
        float pf = at[t][1] + bias0t[t][1] + wi0t[t][1]*xb;
        float pg = at[t][2] + bias0t[t][2] + wi0t[t][2]*xb;
        float po = at[t][3] + bias0t[t][3] + wi0t[t][3]*xb;
        c0[t]  = sigf(pf)*c0[t] + sigf(pi)*thf(pg);
        h0n[t] = sigf(po)*thf(c0[t]);
        stage[(lcol << 3) + q + t*4] = (f16)h0n[t];
      }
    }
    __syncthreads();
    if (tid < 128){
      u32x4 v = ((const u32x4*)stage)[tid];
      st_dwordx4_sc((char*)(H0 + dst*262144 + (hgrp << 11) + (bgrp << 10)) + tid*16, v);
    }
    ++ep; gbar(flagsH, gflagsH, ep, tid, hgrp, true);   // mid barrier WITH inv

    // ========= phase B: gates1 = Wih1*h0new + Whh1*h1  [LDS weights, fp16 h] =========
    float h1n[2];
    {
      const f16* b0 = H0 + dst*262144 + base_h;
      const f16* b1 = H1 + src*262144 + base_h;
      f16x8 X0[2][4], X1[2][4];
      f32x4 acc0 = (f32x4){0,0,0,0}, acc1 = (f32x4){0,0,0,0};
#define LDB(B, CB) { _Pragma("unroll") for (int i = 0; i < 4; ++i){ const int c = (CB)+i; \
      X0[B][i] = *(const f16x8*)(b0 + c*8192); \
      X1[B][i] = *(const f16x8*)(b1 + c*8192); } }
#define MMB(B, CB) { _Pragma("unroll") for (int i = 0; i < 4; ++i){ const int c = (CB)+i; \
      f16x8 wa0 = *(const f16x8*)(lds + ((2*c  ) << 9) + (l << 3)); \
      f16x8 wa1 = *(const f16x8*)(lds + ((2*c+1) << 9) + (l << 3)); \
      f16x8 wb0 = *(const f16x8*)(lds + 32768 + ((2*c  ) << 9) + (l << 3)); \
      f16x8 wb1 = *(const f16x8*)(lds + 32768 + ((2*c+1) << 9) + (l << 3)); \
      acc0 = MFMA16(wa0, X0[B][i], acc0); \
      acc0 = MFMA16(wb0, X1[B][i], acc0); \
      acc1 = MFMA16(wa1, X0[B][i], acc1); \
      acc1 = MFMA16(wb1, X1[B][i], acc1); } }
      LDB(0, 0)
#pragma unroll
      for (int cb = 0; cb < 8; ++cb){
        if ((cb & 1) == 0){ if (cb < 7) LDB(1, (cb+1)*4) MMB(0, cb*4) }
        else              { if (cb < 7) LDB(0, (cb+1)*4) MMB(1, cb*4) }
      }
#undef LDB
#undef MMB
      f32x4 at[2] = {acc0, acc1};
#pragma unroll
      for (int t = 0; t < 2; ++t){
        float pi = at[t][0] + bias1t[t][0];
        float pf = at[t][1] + bias1t[t][1];
        float pg = at[t][2] + bias1t[t][2];
        float po = at[t][3] + bias1t[t][3];
        c1[t]  = sigf(pf)*c1[t] + sigf(pi)*thf(pg);
        h1n[t] = sigf(po)*thf(c1[t]);
        stage[(lcol << 3) + q + t*4] = (f16)h1n[t];
      }
    }
    __syncthreads();
    if (tid < 128){
      u32x4 v = ((const u32x4*)stage)[tid];
      st_dwordx4_sc((char*)(H1 + dst*262144 + (hgrp << 11) + (bgrp << 10)) + tid*16, v);
    }
    __syncthreads();   // protect stage from next phase-A overwrite

    // ---- prefetch next step's phase-A h groups 0,1 (final + L2-fresh here;
    //      rides through fc + end barrier into next iteration) ----
    {
      const f16* a0n = H0 + dst*262144 + base_h;
#pragma unroll
      for (int i = 0; i < 4; ++i){
        BhP[0][i] = *(const f16x8*)(a0n + i*8192);
        BhP[1][i] = *(const f16x8*)(a0n + (4+i)*8192);
      }
    }

    // ---- fc partials with exact JAX dropout (tau = s-83) ----
    if (s >= 83){
      const int tau = s - 83;
      uint2 fk = tf2x32(0u, 42u, 0u, (unsigned)tau);
      unsigned n0 = ((unsigned)bcol << 10) + (unsigned)(j0 + q);
      unsigned n1 = n0 + 4u;
      float v = (drop_keep(fk, n0) ? h1n[0]*fcw0 : 0.f)
              + (drop_keep(fk, n1) ? h1n[1]*fcw1 : 0.f);
      v += __shfl_xor(v, 16, 64);
      v += __shfl_xor(v, 32, 64);
      if (q == 0) atomicAdd(y_acc + (tau << 8) + bcol, v);
      ++ep; gbar(flagsH, gflagsH, ep, tid, hgrp, false);  // end barrier, NO inv
    }
  }

  // tail: y_23 (LLC-coherent read)
  if (hgrp == 0 && q == 0)
    out[bcol*24 + 23] = fcb + __uint_as_float(ld_dword_sc(y_acc + (23 << 8) + bcol));
}

extern "C" void kernel_launch(void* const* d_in, const int* in_sizes, int n_in,
                              void* d_out, int out_size, void* d_ws, size_t ws_size,
                              hipStream_t stream)
{
  const float* x    = (const float*)d_in[0];
  const float* cw   = (const float*)d_in[1];
  const float* cb   = (const float*)d_in[2];
  const float* Wih0 = (const float*)d_in[3];
  const float* Whh0 = (const float*)d_in[4];
  const float* bih0 = (const float*)d_in[5];
  const float* bhh0 = (const float*)d_in[6];
  const float* Wih1 = (const float*)d_in[7];
  const float* Whh1 = (const float*)d_in[8];
  const float* bih1 = (const float*)d_in[9];
  const float* bhh1 = (const float*)d_in[10];
  const float* fc_w = (const float*)d_in[11];
  const float* fc_b = (const float*)d_in[12];
  float* out = (float*)d_out;
  char*  ws  = (char*)d_ws;

  hipLaunchKernelGGL(k_init, dim3(1040), dim3(256), 0, stream,
                     (uint4*)(ws + H0_OFF), (uint4*)(ws + YACC_OFF), (uint4*)(ws + FLAG_OFF));
  hipLaunchKernelGGL(k_seq,  dim3(84), dim3(256), 0, stream, x, cw, cb, (float*)(ws + SEQ_OFF));
  hipLaunchKernelGGL(k_wpack, dim3(128), dim3(512), 0, stream, Whh0, (f16*)(ws + WHH0F_OFF));
  hipLaunchKernelGGL(k_main, dim3(256), dim3(512), 149504, stream,
                     Wih0, Whh0, bih0, bhh0, Wih1, Whh1, bih1, bhh1,
                     fc_w, fc_b, ws, out);
}